// Round 2
// baseline (890.839 us; speedup 1.0000x reference)
//
#include <hip/hip_runtime.h>
#include <math.h>

#define NN 500000
#define NB 8192
#define GMAX 16
#define HG_GRID 1024
#define HG_NT ((NN + 63) / 64)

typedef _Float16 f16x8 __attribute__((ext_vector_type(8)));
typedef __fp16 fp16x2 __attribute__((ext_vector_type(2)));
typedef float f32x4 __attribute__((ext_vector_type(4)));

__device__ inline f16x8 cvt8(float4 a, float4 b) {
    union { fp16x2 p[4]; f16x8 r; } u;
    u.p[0] = __builtin_amdgcn_cvt_pkrtz(a.x, a.y);
    u.p[1] = __builtin_amdgcn_cvt_pkrtz(a.z, a.w);
    u.p[2] = __builtin_amdgcn_cvt_pkrtz(b.x, b.y);
    u.p[3] = __builtin_amdgcn_cvt_pkrtz(b.z, b.w);
    return u.r;
}

// ---------------- weight prep: W^T as f16 ----------------
__global__ void prep_w(const float* __restrict__ nw1, const float* __restrict__ nw2,
                       const float* __restrict__ gw1, const float* __restrict__ gw2,
                       const float* __restrict__ qw1, const float* __restrict__ qw2,
                       _Float16* __restrict__ wT1, _Float16* __restrict__ wT2,
                       _Float16* __restrict__ wTg, _Float16* __restrict__ wTq1,
                       _Float16* __restrict__ wTq2, _Float16* __restrict__ g2h) {
    int k = blockIdx.x;   // input dim
    int n = threadIdx.x;  // output dim
    wT1[n * 128 + k]  = (_Float16)nw1[k * 128 + n];
    wT2[n * 128 + k]  = (_Float16)nw2[k * 128 + n];
    wTg[n * 128 + k]  = (_Float16)gw1[k * 128 + n];
    wTq1[n * 128 + k] = (_Float16)qw1[k * 128 + n];
    wTq2[n * 128 + k] = (_Float16)qw2[k * 128 + n];
    if (k == 0) g2h[n] = (_Float16)gw2[n];
}

// ---------------- ques MLP via MFMA (q stored f16) + zero Ppre,s ----------------
__launch_bounds__(512, 4)
__global__ void q_kernel(const float* __restrict__ u,
                         const _Float16* __restrict__ wTq1, const _Float16* __restrict__ wTq2,
                         const float* __restrict__ qb1, const float* __restrict__ qb2,
                         _Float16* __restrict__ q, float* __restrict__ Ppre, float* __restrict__ s) {
    __shared__ __align__(16) _Float16 tbuf[128][136];
    const int tid  = threadIdx.x;
    const int wave = tid >> 6;
    const int lane = tid & 63;
    const int lrow = lane & 15;
    const int quad = lane >> 4;
    const int wr   = wave >> 1;
    const int wc   = wave & 1;
    const int row0 = blockIdx.x * 128;
    const int rbase = wr * 32;

    for (int idx = tid; idx < 128 * 128; idx += 512) Ppre[(size_t)row0 * 128 + idx] = 0.f;
    if (tid < 128) s[row0 + tid] = 0.f;

    f32x4 acc[2][4];
    const f32x4 fz = {0.f, 0.f, 0.f, 0.f};
#pragma unroll
    for (int mi = 0; mi < 2; ++mi)
#pragma unroll
        for (int ci = 0; ci < 4; ++ci) acc[mi][ci] = fz;

#pragma unroll
    for (int ki = 0; ki < 4; ++ki) {
        const int k = ki * 32 + quad * 8;
        f16x8 a[2];
#pragma unroll
        for (int mi = 0; mi < 2; ++mi) {
            int r = row0 + rbase + mi * 16 + lrow;
            const float4* up = (const float4*)(u + (size_t)r * 128 + k);
            a[mi] = cvt8(up[0], up[1]);
        }
        f16x8 b[4];
#pragma unroll
        for (int ci = 0; ci < 4; ++ci)
            b[ci] = *(const f16x8*)(wTq1 + (size_t)(wc * 64 + ci * 16 + lrow) * 128 + k);
#pragma unroll
        for (int mi = 0; mi < 2; ++mi)
#pragma unroll
            for (int ci = 0; ci < 4; ++ci)
                acc[mi][ci] = __builtin_amdgcn_mfma_f32_16x16x32_f16(a[mi], b[ci], acc[mi][ci], 0, 0, 0);
    }
#pragma unroll
    for (int ci = 0; ci < 4; ++ci) {
        int c = wc * 64 + ci * 16 + lrow;
        float bv = qb1[c];
#pragma unroll
        for (int mi = 0; mi < 2; ++mi)
#pragma unroll
            for (int i = 0; i < 4; ++i) {
                int r = rbase + mi * 16 + quad * 4 + i;
                tbuf[r][c] = (_Float16)fmaxf(acc[mi][ci][i] + bv, 0.f);
            }
    }
    __syncthreads();

#pragma unroll
    for (int mi = 0; mi < 2; ++mi)
#pragma unroll
        for (int ci = 0; ci < 4; ++ci) acc[mi][ci] = fz;
#pragma unroll
    for (int ki = 0; ki < 4; ++ki) {
        const int k = ki * 32 + quad * 8;
        f16x8 a[2];
#pragma unroll
        for (int mi = 0; mi < 2; ++mi)
            a[mi] = *(const f16x8*)&tbuf[rbase + mi * 16 + lrow][k];
        f16x8 b[4];
#pragma unroll
        for (int ci = 0; ci < 4; ++ci)
            b[ci] = *(const f16x8*)(wTq2 + (size_t)(wc * 64 + ci * 16 + lrow) * 128 + k);
#pragma unroll
        for (int mi = 0; mi < 2; ++mi)
#pragma unroll
            for (int ci = 0; ci < 4; ++ci)
                acc[mi][ci] = __builtin_amdgcn_mfma_f32_16x16x32_f16(a[mi], b[ci], acc[mi][ci], 0, 0, 0);
    }
#pragma unroll
    for (int ci = 0; ci < 4; ++ci) {
        int c = wc * 64 + ci * 16 + lrow;
        float bv = qb2[c];
#pragma unroll
        for (int mi = 0; mi < 2; ++mi)
#pragma unroll
            for (int i = 0; i < 4; ++i) {
                int r = row0 + rbase + mi * 16 + quad * 4 + i;
                q[(size_t)r * 128 + c] = (_Float16)(acc[mi][ci][i] + bv);
            }
    }
}

// ---------------- fused node-MLP + gate + pool-over-t1 (PERSISTENT + x prefetch) ----------------
__launch_bounds__(256, 4)
__global__ void hg_kernel(const float* __restrict__ x, const int* __restrict__ batch,
                          const _Float16* __restrict__ qglob,
                          const _Float16* __restrict__ wT1, const _Float16* __restrict__ wT2,
                          const _Float16* __restrict__ wTg, const _Float16* __restrict__ g2h,
                          const float* __restrict__ nb1, const float* __restrict__ nb2,
                          const float* __restrict__ gb1, const float* __restrict__ gb2,
                          float* __restrict__ Ppre, float* __restrict__ s) {
    __shared__ __align__(16) _Float16 t1buf[64][136];    // persists: M1 out -> M2 in -> pooling B
    __shared__ __align__(16) _Float16 scratch[64][136];  // gin only
    __shared__ __align__(16) _Float16 qsE[GMAX][136];    // union: qs (f16) then E selector
    __shared__ float gpart[2][64];
    __shared__ float sacc[GMAX];
    __shared__ int batch_t[64];
    __shared__ int maxrel_sh;

    const int tid  = threadIdx.x;
    const int wave = tid >> 6;   // 0..3
    const int lane = tid & 63;
    const int lrow = lane & 15;
    const int quad = lane >> 4;
    const int wr   = wave >> 1;  // 0..1
    const int wc   = wave & 1;
    const int rbase = wr * 32;
    const int blk  = (int)blockIdx.x;

    const f32x4 fz = {0.f, 0.f, 0.f, 0.f};

    // ---- prologue: prefetch x-tile + batch window for first tile ----
    float4 xraw[4][2][2];
    {
        const int r0 = blk * 64;
#pragma unroll
        for (int ki = 0; ki < 4; ++ki)
#pragma unroll
            for (int mi = 0; mi < 2; ++mi) {
                int r = min(r0 + rbase + mi * 16 + lrow, NN - 1);
                const float4* xp = (const float4*)(x + (size_t)r * 128 + ki * 32 + quad * 8);
                xraw[ki][mi][0] = xp[0];
                xraw[ki][mi][1] = xp[1];
            }
    }
    int bv = 0;
    if (wave == 0) {
        int i0 = blk * 64 + lane;
        bv = batch[min(i0, NN - 1)];
    }

    for (int t = blk; t < HG_NT; t += HG_GRID) {
        const int row0  = t * 64;
        const int rown0 = (t + HG_GRID) * 64;  // next tile's base (loads are row-clamped)

        // ---- setup: batch window, b_lo, maxrel (wave 0 only; uses prefetched bv) ----
        if (wave == 0) {
            batch_t[lane] = bv;
            int b0 = __shfl(bv, 0, 64);
            int rel = bv - b0;
#pragma unroll
            for (int off = 32; off >= 1; off >>= 1) rel = max(rel, __shfl_xor(rel, off, 64));
            if (lane == 0) maxrel_sh = rel;
        }
        __syncthreads();  // bar0 (also orders prev-iter qsE/t1buf reads vs this iter's writes)
        const int b_lo = batch_t[0];
        const int gcnt = min(maxrel_sh + 1, GMAX);

        // prefetch next tile's batch window (arrives during this tile's compute)
        if (wave == 0) bv = batch[min(rown0 + lane, NN - 1)];

        // qs: gather q rows for graphs in window (consumed after bar1)
        for (int idx = tid; idx < gcnt * 16; idx += 256)
            *(f16x8*)&qsE[idx >> 4][(idx & 15) * 8] =
                *(const f16x8*)(qglob + (size_t)(b_lo + (idx >> 4)) * 128 + (idx & 15) * 8);

        int grel[2][4];
#pragma unroll
        for (int mi = 0; mi < 2; ++mi)
#pragma unroll
            for (int i = 0; i < 4; ++i)
                grel[mi][i] = batch_t[rbase + mi * 16 + quad * 4 + i] - b_lo;

        // convert prefetched x to f16 fragments (frees the f32 prefetch regs)
        f16x8 a16[4][2];
#pragma unroll
        for (int ki = 0; ki < 4; ++ki)
#pragma unroll
            for (int mi = 0; mi < 2; ++mi)
                a16[ki][mi] = cvt8(xraw[ki][mi][0], xraw[ki][mi][1]);

        f32x4 acc[2][4];
#pragma unroll
        for (int mi = 0; mi < 2; ++mi)
#pragma unroll
            for (int ci = 0; ci < 4; ++ci) acc[mi][ci] = fz;

        // ===== M1: t1 = relu(x @ w1 + b1) -> t1buf =====
#pragma unroll
        for (int ki = 0; ki < 4; ++ki) {
            const int k = ki * 32 + quad * 8;
            f16x8 b[4];
#pragma unroll
            for (int ci = 0; ci < 4; ++ci)
                b[ci] = *(const f16x8*)(wT1 + (size_t)(wc * 64 + ci * 16 + lrow) * 128 + k);
#pragma unroll
            for (int mi = 0; mi < 2; ++mi)
#pragma unroll
                for (int ci = 0; ci < 4; ++ci)
                    acc[mi][ci] = __builtin_amdgcn_mfma_f32_16x16x32_f16(a16[ki][mi], b[ci], acc[mi][ci], 0, 0, 0);
        }
#pragma unroll
        for (int ci = 0; ci < 4; ++ci) {
            int c = wc * 64 + ci * 16 + lrow;
            float bvv = nb1[c];
#pragma unroll
            for (int mi = 0; mi < 2; ++mi)
#pragma unroll
                for (int i = 0; i < 4; ++i) {
                    int r = rbase + mi * 16 + quad * 4 + i;
                    t1buf[r][c] = (_Float16)fmaxf(acc[mi][ci][i] + bvv, 0.f);
                }
        }
        __syncthreads();  // bar1: t1 + qs visible

        // ---- issue next tile's x loads NOW (f32 regs free; lands during M2..pool) ----
#pragma unroll
        for (int ki = 0; ki < 4; ++ki)
#pragma unroll
            for (int mi = 0; mi < 2; ++mi) {
                int r = min(rown0 + rbase + mi * 16 + lrow, NN - 1);
                const float4* xp = (const float4*)(x + (size_t)r * 128 + ki * 32 + quad * 8);
                xraw[ki][mi][0] = xp[0];
                xraw[ki][mi][1] = xp[1];
            }

        // ===== M2: h = t1 @ w2 + b2 ; gin = q[batch] * h -> scratch =====
#pragma unroll
        for (int mi = 0; mi < 2; ++mi)
#pragma unroll
            for (int ci = 0; ci < 4; ++ci) acc[mi][ci] = fz;
#pragma unroll
        for (int ki = 0; ki < 4; ++ki) {
            const int k = ki * 32 + quad * 8;
            f16x8 a[2];
#pragma unroll
            for (int mi = 0; mi < 2; ++mi)
                a[mi] = *(const f16x8*)&t1buf[rbase + mi * 16 + lrow][k];
            f16x8 b[4];
#pragma unroll
            for (int ci = 0; ci < 4; ++ci)
                b[ci] = *(const f16x8*)(wT2 + (size_t)(wc * 64 + ci * 16 + lrow) * 128 + k);
#pragma unroll
            for (int mi = 0; mi < 2; ++mi)
#pragma unroll
                for (int ci = 0; ci < 4; ++ci)
                    acc[mi][ci] = __builtin_amdgcn_mfma_f32_16x16x32_f16(a[mi], b[ci], acc[mi][ci], 0, 0, 0);
        }
#pragma unroll
        for (int ci = 0; ci < 4; ++ci) {
            int c = wc * 64 + ci * 16 + lrow;
            float bvv = nb2[c];
#pragma unroll
            for (int mi = 0; mi < 2; ++mi)
#pragma unroll
                for (int i = 0; i < 4; ++i) {
                    int r = rbase + mi * 16 + quad * 4 + i;
                    float h = acc[mi][ci][i] + bvv;
                    int g = grel[mi][i];
                    float qv = (g < GMAX) ? (float)qsE[g][c]
                                          : (float)qglob[(size_t)(b_lo + g) * 128 + c];
                    scratch[r][c] = (_Float16)(qv * h);
                }
        }
        __syncthreads();  // bar2: gin visible, qs reads done

        // zero E + sacc (visible after bar3)
        for (int idx = tid; idx < GMAX * 136 / 2; idx += 256) ((float*)qsE)[idx] = 0.f;
        if (tid < GMAX) sacc[tid] = 0.f;

        // ===== M3: t2 = relu(gin @ gw1 + gb1); gate partial via gw2 dot + shuffle =====
#pragma unroll
        for (int mi = 0; mi < 2; ++mi)
#pragma unroll
            for (int ci = 0; ci < 4; ++ci) acc[mi][ci] = fz;
        float g2hreg[4];
#pragma unroll
        for (int ci = 0; ci < 4; ++ci) g2hreg[ci] = (float)g2h[wc * 64 + ci * 16 + lrow];
#pragma unroll
        for (int ki = 0; ki < 4; ++ki) {
            const int k = ki * 32 + quad * 8;
            f16x8 a[2];
#pragma unroll
            for (int mi = 0; mi < 2; ++mi)
                a[mi] = *(const f16x8*)&scratch[rbase + mi * 16 + lrow][k];
            f16x8 b[4];
#pragma unroll
            for (int ci = 0; ci < 4; ++ci)
                b[ci] = *(const f16x8*)(wTg + (size_t)(wc * 64 + ci * 16 + lrow) * 128 + k);
#pragma unroll
            for (int mi = 0; mi < 2; ++mi)
#pragma unroll
                for (int ci = 0; ci < 4; ++ci)
                    acc[mi][ci] = __builtin_amdgcn_mfma_f32_16x16x32_f16(a[mi], b[ci], acc[mi][ci], 0, 0, 0);
        }
        float p[2][4] = {{0.f, 0.f, 0.f, 0.f}, {0.f, 0.f, 0.f, 0.f}};
#pragma unroll
        for (int ci = 0; ci < 4; ++ci) {
            int c = wc * 64 + ci * 16 + lrow;
            float bvv = gb1[c];
            float w = g2hreg[ci];
#pragma unroll
            for (int mi = 0; mi < 2; ++mi)
#pragma unroll
                for (int i = 0; i < 4; ++i)
                    p[mi][i] = fmaf(fmaxf(acc[mi][ci][i] + bvv, 0.f), w, p[mi][i]);
        }
#pragma unroll
        for (int off = 1; off <= 8; off <<= 1)
#pragma unroll
            for (int mi = 0; mi < 2; ++mi)
#pragma unroll
                for (int i = 0; i < 4; ++i)
                    p[mi][i] += __shfl_xor(p[mi][i], off, 64);
        if (lrow == 0) {
#pragma unroll
            for (int mi = 0; mi < 2; ++mi)
#pragma unroll
                for (int i = 0; i < 4; ++i)
                    gpart[wc][rbase + mi * 16 + quad * 4 + i] = p[mi][i];
        }
        __syncthreads();  // bar3: gpart + E-zero visible

        // ===== gate -> e -> E selector (one thread per row) =====
        const float gb2v = gb2[0];
        if (tid < 64) {
            int r = tid;
            int g = batch_t[r] - b_lo;
            bool valid = (row0 + r) < NN;
            float e = valid ? __expf(gpart[0][r] + gpart[1][r] + gb2v) : 0.f;
            if (g < GMAX) {
                qsE[g][r] = (_Float16)e;
                atomicAdd(&sacc[g], e);
            } else if (valid) {  // pathological >16 graphs per 64-row window
                atomicAdd(&s[b_lo + g], e);
                for (int c = 0; c < 128; ++c)
                    atomicAdd(&Ppre[(size_t)(b_lo + g) * 128 + c], e * (float)t1buf[r][c]);
            }
        }
        __syncthreads();  // bar4: E visible

        // ===== pooling: Ppre_tile = E(16x64) @ T1(64x128), each wave 32 cols =====
        f16x8 aE[2];
#pragma unroll
        for (int ki = 0; ki < 2; ++ki)
            aE[ki] = *(const f16x8*)&qsE[lrow][ki * 32 + quad * 8];
        f32x4 pacc[2] = {fz, fz};
#pragma unroll
        for (int ci2 = 0; ci2 < 2; ++ci2) {
            int col = wave * 32 + ci2 * 16 + lrow;
#pragma unroll
            for (int ki = 0; ki < 2; ++ki) {
                f16x8 bh;
#pragma unroll
                for (int j = 0; j < 8; ++j) bh[j] = t1buf[ki * 32 + quad * 8 + j][col];
                pacc[ci2] = __builtin_amdgcn_mfma_f32_16x16x32_f16(aE[ki], bh, pacc[ci2], 0, 0, 0);
            }
        }
#pragma unroll
        for (int ci2 = 0; ci2 < 2; ++ci2)
#pragma unroll
            for (int i = 0; i < 4; ++i) {
                int g = quad * 4 + i;
                if (g < gcnt)
                    atomicAdd(&Ppre[(size_t)(b_lo + g) * 128 + wave * 32 + ci2 * 16 + lrow], pacc[ci2][i]);
            }
        if (tid < gcnt) atomicAdd(&s[b_lo + tid], sacc[tid]);
    }
}

// ---------------- finalize: out = (Ppre @ w2 + s*b2) / (s + eps) ----------------
__launch_bounds__(512, 4)
__global__ void fin_kernel(const float* __restrict__ Ppre, const float* __restrict__ s,
                           const _Float16* __restrict__ wT2, const float* __restrict__ nb2,
                           float* __restrict__ out) {
    const int tid  = threadIdx.x;
    const int wave = tid >> 6;
    const int lane = tid & 63;
    const int lrow = lane & 15;
    const int quad = lane >> 4;
    const int wr   = wave >> 1;
    const int wc   = wave & 1;
    const int row0 = blockIdx.x * 128;
    const int rbase = wr * 32;

    f32x4 acc[2][4];
    const f32x4 fz = {0.f, 0.f, 0.f, 0.f};
#pragma unroll
    for (int mi = 0; mi < 2; ++mi)
#pragma unroll
        for (int ci = 0; ci < 4; ++ci) acc[mi][ci] = fz;
#pragma unroll
    for (int ki = 0; ki < 4; ++ki) {
        const int k = ki * 32 + quad * 8;
        f16x8 a[2];
#pragma unroll
        for (int mi = 0; mi < 2; ++mi) {
            int r = row0 + rbase + mi * 16 + lrow;
            const float4* pp = (const float4*)(Ppre + (size_t)r * 128 + k);
            a[mi] = cvt8(pp[0], pp[1]);
        }
        f16x8 b[4];
#pragma unroll
        for (int ci = 0; ci < 4; ++ci)
            b[ci] = *(const f16x8*)(wT2 + (size_t)(wc * 64 + ci * 16 + lrow) * 128 + k);
#pragma unroll
        for (int mi = 0; mi < 2; ++mi)
#pragma unroll
            for (int ci = 0; ci < 4; ++ci)
                acc[mi][ci] = __builtin_amdgcn_mfma_f32_16x16x32_f16(a[mi], b[ci], acc[mi][ci], 0, 0, 0);
    }
    float sv[2][4], rinv[2][4];
#pragma unroll
    for (int mi = 0; mi < 2; ++mi)
#pragma unroll
        for (int i = 0; i < 4; ++i) {
            int r = row0 + rbase + mi * 16 + quad * 4 + i;
            sv[mi][i] = s[r];
            rinv[mi][i] = 1.f / (sv[mi][i] + 1e-16f);
        }
#pragma unroll
    for (int ci = 0; ci < 4; ++ci) {
        int c = wc * 64 + ci * 16 + lrow;
        float bv = nb2[c];
#pragma unroll
        for (int mi = 0; mi < 2; ++mi)
#pragma unroll
            for (int i = 0; i < 4; ++i) {
                int r = row0 + rbase + mi * 16 + quad * 4 + i;
                out[(size_t)r * 128 + c] = (acc[mi][ci][i] + sv[mi][i] * bv) * rinv[mi][i];
            }
    }
}

extern "C" void kernel_launch(void* const* d_in, const int* in_sizes, int n_in,
                              void* d_out, int out_size, void* d_ws, size_t ws_size,
                              hipStream_t stream) {
    const float* x    = (const float*)d_in[0];
    const float* u    = (const float*)d_in[1];
    const int* batch  = (const int*)d_in[2];
    const float* gw1  = (const float*)d_in[4];
    const float* gb1  = (const float*)d_in[5];
    const float* gw2  = (const float*)d_in[6];
    const float* gb2  = (const float*)d_in[7];
    const float* nw1  = (const float*)d_in[8];
    const float* nb1  = (const float*)d_in[9];
    const float* nw2  = (const float*)d_in[10];
    const float* nb2  = (const float*)d_in[11];
    const float* qw1  = (const float*)d_in[12];
    const float* qb1  = (const float*)d_in[13];
    const float* qw2  = (const float*)d_in[14];
    const float* qb2  = (const float*)d_in[15];

    char* ws = (char*)d_ws;
    _Float16* q   = (_Float16*)ws;                       // 2 MB
    float* Ppre   = (float*)(ws + 2097152);              // 4 MB
    float* s      = (float*)(ws + 6291456);              // 32 KB
    _Float16* wT1 = (_Float16*)(ws + 6324224);           // 5 x 32 KB + g2h
    _Float16* wT2  = wT1 + 16384;
    _Float16* wTg  = wT2 + 16384;
    _Float16* wTq1 = wTg + 16384;
    _Float16* wTq2 = wTq1 + 16384;
    _Float16* g2h  = wTq2 + 16384;
    float* out = (float*)d_out;

    hipLaunchKernelGGL(prep_w, dim3(128), dim3(128), 0, stream,
                       nw1, nw2, gw1, gw2, qw1, qw2, wT1, wT2, wTg, wTq1, wTq2, g2h);
    hipLaunchKernelGGL(q_kernel, dim3(NB / 128), dim3(512), 0, stream,
                       u, wTq1, wTq2, qb1, qb2, q, Ppre, s);
    hipLaunchKernelGGL(hg_kernel, dim3(HG_GRID), dim3(256), 0, stream,
                       x, batch, q, wT1, wT2, wTg, g2h, nb1, nb2, gb1, gb2, Ppre, s);
    hipLaunchKernelGGL(fin_kernel, dim3(NB / 128), dim3(512), 0, stream,
                       Ppre, s, wT2, nb2, out);
}

// Round 3
// 742.094 us; speedup vs baseline: 1.2004x; 1.2004x over previous
//
#include <hip/hip_runtime.h>
#include <math.h>

#define NN 500000
#define NB 8192
#define GMAX 16
#define HG_GRID 768
#define HG_NT ((NN + 63) / 64)

typedef _Float16 f16x8 __attribute__((ext_vector_type(8)));
typedef __fp16 fp16x2 __attribute__((ext_vector_type(2)));
typedef float f32x4 __attribute__((ext_vector_type(4)));

__device__ inline f16x8 cvt8(float4 a, float4 b) {
    union { fp16x2 p[4]; f16x8 r; } u;
    u.p[0] = __builtin_amdgcn_cvt_pkrtz(a.x, a.y);
    u.p[1] = __builtin_amdgcn_cvt_pkrtz(a.z, a.w);
    u.p[2] = __builtin_amdgcn_cvt_pkrtz(b.x, b.y);
    u.p[3] = __builtin_amdgcn_cvt_pkrtz(b.z, b.w);
    return u.r;
}

// ---------------- weight prep: W^T as f16 ----------------
__global__ void prep_w(const float* __restrict__ nw1, const float* __restrict__ nw2,
                       const float* __restrict__ gw1, const float* __restrict__ gw2,
                       const float* __restrict__ qw1, const float* __restrict__ qw2,
                       _Float16* __restrict__ wT1, _Float16* __restrict__ wT2,
                       _Float16* __restrict__ wTg, _Float16* __restrict__ wTq1,
                       _Float16* __restrict__ wTq2, _Float16* __restrict__ g2h) {
    int k = blockIdx.x;   // input dim
    int n = threadIdx.x;  // output dim
    wT1[n * 128 + k]  = (_Float16)nw1[k * 128 + n];
    wT2[n * 128 + k]  = (_Float16)nw2[k * 128 + n];
    wTg[n * 128 + k]  = (_Float16)gw1[k * 128 + n];
    wTq1[n * 128 + k] = (_Float16)qw1[k * 128 + n];
    wTq2[n * 128 + k] = (_Float16)qw2[k * 128 + n];
    if (k == 0) g2h[n] = (_Float16)gw2[n];
}

// ---------------- ques MLP via MFMA (q stored f16) + zero Ppre,s ----------------
__launch_bounds__(512, 4)
__global__ void q_kernel(const float* __restrict__ u,
                         const _Float16* __restrict__ wTq1, const _Float16* __restrict__ wTq2,
                         const float* __restrict__ qb1, const float* __restrict__ qb2,
                         _Float16* __restrict__ q, float* __restrict__ Ppre, float* __restrict__ s) {
    __shared__ __align__(16) _Float16 tbuf[128][136];
    const int tid  = threadIdx.x;
    const int wave = tid >> 6;
    const int lane = tid & 63;
    const int lrow = lane & 15;
    const int quad = lane >> 4;
    const int wr   = wave >> 1;
    const int wc   = wave & 1;
    const int row0 = blockIdx.x * 128;
    const int rbase = wr * 32;

    for (int idx = tid; idx < 128 * 128; idx += 512) Ppre[(size_t)row0 * 128 + idx] = 0.f;
    if (tid < 128) s[row0 + tid] = 0.f;

    f32x4 acc[2][4];
    const f32x4 fz = {0.f, 0.f, 0.f, 0.f};
#pragma unroll
    for (int mi = 0; mi < 2; ++mi)
#pragma unroll
        for (int ci = 0; ci < 4; ++ci) acc[mi][ci] = fz;

#pragma unroll
    for (int ki = 0; ki < 4; ++ki) {
        const int k = ki * 32 + quad * 8;
        f16x8 a[2];
#pragma unroll
        for (int mi = 0; mi < 2; ++mi) {
            int r = row0 + rbase + mi * 16 + lrow;
            const float4* up = (const float4*)(u + (size_t)r * 128 + k);
            a[mi] = cvt8(up[0], up[1]);
        }
        f16x8 b[4];
#pragma unroll
        for (int ci = 0; ci < 4; ++ci)
            b[ci] = *(const f16x8*)(wTq1 + (size_t)(wc * 64 + ci * 16 + lrow) * 128 + k);
#pragma unroll
        for (int mi = 0; mi < 2; ++mi)
#pragma unroll
            for (int ci = 0; ci < 4; ++ci)
                acc[mi][ci] = __builtin_amdgcn_mfma_f32_16x16x32_f16(a[mi], b[ci], acc[mi][ci], 0, 0, 0);
    }
#pragma unroll
    for (int ci = 0; ci < 4; ++ci) {
        int c = wc * 64 + ci * 16 + lrow;
        float bv = qb1[c];
#pragma unroll
        for (int mi = 0; mi < 2; ++mi)
#pragma unroll
            for (int i = 0; i < 4; ++i) {
                int r = rbase + mi * 16 + quad * 4 + i;
                tbuf[r][c] = (_Float16)fmaxf(acc[mi][ci][i] + bv, 0.f);
            }
    }
    __syncthreads();

#pragma unroll
    for (int mi = 0; mi < 2; ++mi)
#pragma unroll
        for (int ci = 0; ci < 4; ++ci) acc[mi][ci] = fz;
#pragma unroll
    for (int ki = 0; ki < 4; ++ki) {
        const int k = ki * 32 + quad * 8;
        f16x8 a[2];
#pragma unroll
        for (int mi = 0; mi < 2; ++mi)
            a[mi] = *(const f16x8*)&tbuf[rbase + mi * 16 + lrow][k];
        f16x8 b[4];
#pragma unroll
        for (int ci = 0; ci < 4; ++ci)
            b[ci] = *(const f16x8*)(wTq2 + (size_t)(wc * 64 + ci * 16 + lrow) * 128 + k);
#pragma unroll
        for (int mi = 0; mi < 2; ++mi)
#pragma unroll
            for (int ci = 0; ci < 4; ++ci)
                acc[mi][ci] = __builtin_amdgcn_mfma_f32_16x16x32_f16(a[mi], b[ci], acc[mi][ci], 0, 0, 0);
    }
#pragma unroll
    for (int ci = 0; ci < 4; ++ci) {
        int c = wc * 64 + ci * 16 + lrow;
        float bv = qb2[c];
#pragma unroll
        for (int mi = 0; mi < 2; ++mi)
#pragma unroll
            for (int i = 0; i < 4; ++i) {
                int r = row0 + rbase + mi * 16 + quad * 4 + i;
                q[(size_t)r * 128 + c] = (_Float16)(acc[mi][ci][i] + bv);
            }
    }
}

// ---------------- fused node-MLP + gate + pool-over-t1 (PERSISTENT + x prefetch) ----------------
// launch_bounds(256,3): VGPR cap ~170 so the 64-reg xraw prefetch does NOT spill
// (round 2 post-mortem: (256,4) cap=128 spilled all of xraw -> +1.1GB scratch traffic).
__launch_bounds__(256, 3)
__global__ void hg_kernel(const float* __restrict__ x, const int* __restrict__ batch,
                          const _Float16* __restrict__ qglob,
                          const _Float16* __restrict__ wT1, const _Float16* __restrict__ wT2,
                          const _Float16* __restrict__ wTg, const _Float16* __restrict__ g2h,
                          const float* __restrict__ nb1, const float* __restrict__ nb2,
                          const float* __restrict__ gb1, const float* __restrict__ gb2,
                          float* __restrict__ Ppre, float* __restrict__ s) {
    __shared__ __align__(16) _Float16 t1buf[64][136];    // persists: M1 out -> M2 in -> pooling B
    __shared__ __align__(16) _Float16 scratch[64][136];  // gin only
    __shared__ __align__(16) _Float16 qsE[GMAX][136];    // union: qs (f16) then E selector
    __shared__ float gpart[2][64];
    __shared__ float sacc[GMAX];
    __shared__ int batch_t[64];
    __shared__ int maxrel_sh;

    const int tid  = threadIdx.x;
    const int wave = tid >> 6;   // 0..3
    const int lane = tid & 63;
    const int lrow = lane & 15;
    const int quad = lane >> 4;
    const int wr   = wave >> 1;  // 0..1
    const int wc   = wave & 1;
    const int rbase = wr * 32;
    const int blk  = (int)blockIdx.x;

    const f32x4 fz = {0.f, 0.f, 0.f, 0.f};

    // ---- prologue: load + convert first tile; prefetch first batch window ----
    f16x8 a16[4][2];   // CURRENT tile's A fragments (f16, 32 VGPRs) — crosses loop top
    {
        const int r0 = blk * 64;
#pragma unroll
        for (int ki = 0; ki < 4; ++ki)
#pragma unroll
            for (int mi = 0; mi < 2; ++mi) {
                int r = min(r0 + rbase + mi * 16 + lrow, NN - 1);
                const float4* xp = (const float4*)(x + (size_t)r * 128 + ki * 32 + quad * 8);
                a16[ki][mi] = cvt8(xp[0], xp[1]);
            }
    }
    int bv = 0;
    if (wave == 0) {
        int i0 = blk * 64 + lane;
        bv = batch[min(i0, NN - 1)];
    }

    for (int t = blk; t < HG_NT; t += HG_GRID) {
        const int row0  = t * 64;
        const int rown0 = (t + HG_GRID) * 64;  // next tile's base (loads are row-clamped)

        // ---- setup: batch window, b_lo, maxrel (wave 0 only; uses prefetched bv) ----
        if (wave == 0) {
            batch_t[lane] = bv;
            int b0 = __shfl(bv, 0, 64);
            int rel = bv - b0;
#pragma unroll
            for (int off = 32; off >= 1; off >>= 1) rel = max(rel, __shfl_xor(rel, off, 64));
            if (lane == 0) maxrel_sh = rel;
        }
        __syncthreads();  // bar0 (also orders prev-iter qsE/t1buf reads vs this iter's writes)
        const int b_lo = batch_t[0];
        const int gcnt = min(maxrel_sh + 1, GMAX);

        // prefetch next tile's batch window (arrives during this tile's compute)
        if (wave == 0) bv = batch[min(rown0 + lane, NN - 1)];

        // qs: gather q rows for graphs in window (consumed after bar1)
        for (int idx = tid; idx < gcnt * 16; idx += 256)
            *(f16x8*)&qsE[idx >> 4][(idx & 15) * 8] =
                *(const f16x8*)(qglob + (size_t)(b_lo + (idx >> 4)) * 128 + (idx & 15) * 8);

        int grel[2][4];
#pragma unroll
        for (int mi = 0; mi < 2; ++mi)
#pragma unroll
            for (int i = 0; i < 4; ++i)
                grel[mi][i] = batch_t[rbase + mi * 16 + quad * 4 + i] - b_lo;

        f32x4 acc[2][4];
#pragma unroll
        for (int mi = 0; mi < 2; ++mi)
#pragma unroll
            for (int ci = 0; ci < 4; ++ci) acc[mi][ci] = fz;

        // ===== M1: t1 = relu(x @ w1 + b1) -> t1buf (uses a16 prepared last iter) =====
#pragma unroll
        for (int ki = 0; ki < 4; ++ki) {
            const int k = ki * 32 + quad * 8;
            f16x8 b[4];
#pragma unroll
            for (int ci = 0; ci < 4; ++ci)
                b[ci] = *(const f16x8*)(wT1 + (size_t)(wc * 64 + ci * 16 + lrow) * 128 + k);
#pragma unroll
            for (int mi = 0; mi < 2; ++mi)
#pragma unroll
                for (int ci = 0; ci < 4; ++ci)
                    acc[mi][ci] = __builtin_amdgcn_mfma_f32_16x16x32_f16(a16[ki][mi], b[ci], acc[mi][ci], 0, 0, 0);
        }
#pragma unroll
        for (int ci = 0; ci < 4; ++ci) {
            int c = wc * 64 + ci * 16 + lrow;
            float bvv = nb1[c];
#pragma unroll
            for (int mi = 0; mi < 2; ++mi)
#pragma unroll
                for (int i = 0; i < 4; ++i) {
                    int r = rbase + mi * 16 + quad * 4 + i;
                    t1buf[r][c] = (_Float16)fmaxf(acc[mi][ci][i] + bvv, 0.f);
                }
        }
        __syncthreads();  // bar1: t1 + qs visible

        // ---- issue next tile's x loads NOW (xraw live only bar1 -> bar2) ----
        float4 xraw[4][2][2];
#pragma unroll
        for (int ki = 0; ki < 4; ++ki)
#pragma unroll
            for (int mi = 0; mi < 2; ++mi) {
                int r = min(rown0 + rbase + mi * 16 + lrow, NN - 1);
                const float4* xp = (const float4*)(x + (size_t)r * 128 + ki * 32 + quad * 8);
                xraw[ki][mi][0] = xp[0];
                xraw[ki][mi][1] = xp[1];
            }

        // ===== M2: h = t1 @ w2 + b2 ; gin = q[batch] * h -> scratch =====
#pragma unroll
        for (int mi = 0; mi < 2; ++mi)
#pragma unroll
            for (int ci = 0; ci < 4; ++ci) acc[mi][ci] = fz;
#pragma unroll
        for (int ki = 0; ki < 4; ++ki) {
            const int k = ki * 32 + quad * 8;
            f16x8 a[2];
#pragma unroll
            for (int mi = 0; mi < 2; ++mi)
                a[mi] = *(const f16x8*)&t1buf[rbase + mi * 16 + lrow][k];
            f16x8 b[4];
#pragma unroll
            for (int ci = 0; ci < 4; ++ci)
                b[ci] = *(const f16x8*)(wT2 + (size_t)(wc * 64 + ci * 16 + lrow) * 128 + k);
#pragma unroll
            for (int mi = 0; mi < 2; ++mi)
#pragma unroll
                for (int ci = 0; ci < 4; ++ci)
                    acc[mi][ci] = __builtin_amdgcn_mfma_f32_16x16x32_f16(a[mi], b[ci], acc[mi][ci], 0, 0, 0);
        }
#pragma unroll
        for (int ci = 0; ci < 4; ++ci) {
            int c = wc * 64 + ci * 16 + lrow;
            float bvv = nb2[c];
#pragma unroll
            for (int mi = 0; mi < 2; ++mi)
#pragma unroll
                for (int i = 0; i < 4; ++i) {
                    int r = rbase + mi * 16 + quad * 4 + i;
                    float h = acc[mi][ci][i] + bvv;
                    int g = grel[mi][i];
                    float qv = (g < GMAX) ? (float)qsE[g][c]
                                          : (float)qglob[(size_t)(b_lo + g) * 128 + c];
                    scratch[r][c] = (_Float16)(qv * h);
                }
        }
        __syncthreads();  // bar2: gin visible, qs reads done (implicit vmcnt(0): xraw complete)

        // convert next tile's x to f16 NOW — frees the 64 f32 prefetch regs before M3
        #pragma unroll
        for (int ki = 0; ki < 4; ++ki)
#pragma unroll
            for (int mi = 0; mi < 2; ++mi)
                a16[ki][mi] = cvt8(xraw[ki][mi][0], xraw[ki][mi][1]);

        // zero E + sacc (visible after bar3)
        for (int idx = tid; idx < GMAX * 136 / 2; idx += 256) ((float*)qsE)[idx] = 0.f;
        if (tid < GMAX) sacc[tid] = 0.f;

        // ===== M3: t2 = relu(gin @ gw1 + gb1); gate partial via gw2 dot + shuffle =====
#pragma unroll
        for (int mi = 0; mi < 2; ++mi)
#pragma unroll
            for (int ci = 0; ci < 4; ++ci) acc[mi][ci] = fz;
        float g2hreg[4];
#pragma unroll
        for (int ci = 0; ci < 4; ++ci) g2hreg[ci] = (float)g2h[wc * 64 + ci * 16 + lrow];
#pragma unroll
        for (int ki = 0; ki < 4; ++ki) {
            const int k = ki * 32 + quad * 8;
            f16x8 a[2];
#pragma unroll
            for (int mi = 0; mi < 2; ++mi)
                a[mi] = *(const f16x8*)&scratch[rbase + mi * 16 + lrow][k];
            f16x8 b[4];
#pragma unroll
            for (int ci = 0; ci < 4; ++ci)
                b[ci] = *(const f16x8*)(wTg + (size_t)(wc * 64 + ci * 16 + lrow) * 128 + k);
#pragma unroll
            for (int mi = 0; mi < 2; ++mi)
#pragma unroll
                for (int ci = 0; ci < 4; ++ci)
                    acc[mi][ci] = __builtin_amdgcn_mfma_f32_16x16x32_f16(a[mi], b[ci], acc[mi][ci], 0, 0, 0);
        }
        float p[2][4] = {{0.f, 0.f, 0.f, 0.f}, {0.f, 0.f, 0.f, 0.f}};
#pragma unroll
        for (int ci = 0; ci < 4; ++ci) {
            int c = wc * 64 + ci * 16 + lrow;
            float bvv = gb1[c];
            float w = g2hreg[ci];
#pragma unroll
            for (int mi = 0; mi < 2; ++mi)
#pragma unroll
                for (int i = 0; i < 4; ++i)
                    p[mi][i] = fmaf(fmaxf(acc[mi][ci][i] + bvv, 0.f), w, p[mi][i]);
        }
#pragma unroll
        for (int off = 1; off <= 8; off <<= 1)
#pragma unroll
            for (int mi = 0; mi < 2; ++mi)
#pragma unroll
                for (int i = 0; i < 4; ++i)
                    p[mi][i] += __shfl_xor(p[mi][i], off, 64);
        if (lrow == 0) {
#pragma unroll
            for (int mi = 0; mi < 2; ++mi)
#pragma unroll
                for (int i = 0; i < 4; ++i)
                    gpart[wc][rbase + mi * 16 + quad * 4 + i] = p[mi][i];
        }
        __syncthreads();  // bar3: gpart + E-zero visible

        // ===== gate -> e -> E selector (one thread per row) =====
        const float gb2v = gb2[0];
        if (tid < 64) {
            int r = tid;
            int g = batch_t[r] - b_lo;
            bool valid = (row0 + r) < NN;
            float e = valid ? __expf(gpart[0][r] + gpart[1][r] + gb2v) : 0.f;
            if (g < GMAX) {
                qsE[g][r] = (_Float16)e;
                atomicAdd(&sacc[g], e);
            } else if (valid) {  // pathological >16 graphs per 64-row window
                atomicAdd(&s[b_lo + g], e);
                for (int c = 0; c < 128; ++c)
                    atomicAdd(&Ppre[(size_t)(b_lo + g) * 128 + c], e * (float)t1buf[r][c]);
            }
        }
        __syncthreads();  // bar4: E visible

        // ===== pooling: Ppre_tile = E(16x64) @ T1(64x128), each wave 32 cols =====
        f16x8 aE[2];
#pragma unroll
        for (int ki = 0; ki < 2; ++ki)
            aE[ki] = *(const f16x8*)&qsE[lrow][ki * 32 + quad * 8];
        f32x4 pacc[2] = {fz, fz};
#pragma unroll
        for (int ci2 = 0; ci2 < 2; ++ci2) {
            int col = wave * 32 + ci2 * 16 + lrow;
#pragma unroll
            for (int ki = 0; ki < 2; ++ki) {
                f16x8 bh;
#pragma unroll
                for (int j = 0; j < 8; ++j) bh[j] = t1buf[ki * 32 + quad * 8 + j][col];
                pacc[ci2] = __builtin_amdgcn_mfma_f32_16x16x32_f16(aE[ki], bh, pacc[ci2], 0, 0, 0);
            }
        }
#pragma unroll
        for (int ci2 = 0; ci2 < 2; ++ci2)
#pragma unroll
            for (int i = 0; i < 4; ++i) {
                int g = quad * 4 + i;
                if (g < gcnt)
                    atomicAdd(&Ppre[(size_t)(b_lo + g) * 128 + wave * 32 + ci2 * 16 + lrow], pacc[ci2][i]);
            }
        if (tid < gcnt) atomicAdd(&s[b_lo + tid], sacc[tid]);
    }
}

// ---------------- finalize: out = (Ppre @ w2 + s*b2) / (s + eps) ----------------
__launch_bounds__(512, 4)
__global__ void fin_kernel(const float* __restrict__ Ppre, const float* __restrict__ s,
                           const _Float16* __restrict__ wT2, const float* __restrict__ nb2,
                           float* __restrict__ out) {
    const int tid  = threadIdx.x;
    const int wave = tid >> 6;
    const int lane = tid & 63;
    const int lrow = lane & 15;
    const int quad = lane >> 4;
    const int wr   = wave >> 1;
    const int wc   = wave & 1;
    const int row0 = blockIdx.x * 128;
    const int rbase = wr * 32;

    f32x4 acc[2][4];
    const f32x4 fz = {0.f, 0.f, 0.f, 0.f};
#pragma unroll
    for (int mi = 0; mi < 2; ++mi)
#pragma unroll
        for (int ci = 0; ci < 4; ++ci) acc[mi][ci] = fz;
#pragma unroll
    for (int ki = 0; ki < 4; ++ki) {
        const int k = ki * 32 + quad * 8;
        f16x8 a[2];
#pragma unroll
        for (int mi = 0; mi < 2; ++mi) {
            int r = row0 + rbase + mi * 16 + lrow;
            const float4* pp = (const float4*)(Ppre + (size_t)r * 128 + k);
            a[mi] = cvt8(pp[0], pp[1]);
        }
        f16x8 b[4];
#pragma unroll
        for (int ci = 0; ci < 4; ++ci)
            b[ci] = *(const f16x8*)(wT2 + (size_t)(wc * 64 + ci * 16 + lrow) * 128 + k);
#pragma unroll
        for (int mi = 0; mi < 2; ++mi)
#pragma unroll
            for (int ci = 0; ci < 4; ++ci)
                acc[mi][ci] = __builtin_amdgcn_mfma_f32_16x16x32_f16(a[mi], b[ci], acc[mi][ci], 0, 0, 0);
    }
    float sv[2][4], rinv[2][4];
#pragma unroll
    for (int mi = 0; mi < 2; ++mi)
#pragma unroll
        for (int i = 0; i < 4; ++i) {
            int r = row0 + rbase + mi * 16 + quad * 4 + i;
            sv[mi][i] = s[r];
            rinv[mi][i] = 1.f / (sv[mi][i] + 1e-16f);
        }
#pragma unroll
    for (int ci = 0; ci < 4; ++ci) {
        int c = wc * 64 + ci * 16 + lrow;
        float bv = nb2[c];
#pragma unroll
        for (int mi = 0; mi < 2; ++mi)
#pragma unroll
            for (int i = 0; i < 4; ++i) {
                int r = row0 + rbase + mi * 16 + quad * 4 + i;
                out[(size_t)r * 128 + c] = (acc[mi][ci][i] + sv[mi][i] * bv) * rinv[mi][i];
            }
    }
}

extern "C" void kernel_launch(void* const* d_in, const int* in_sizes, int n_in,
                              void* d_out, int out_size, void* d_ws, size_t ws_size,
                              hipStream_t stream) {
    const float* x    = (const float*)d_in[0];
    const float* u    = (const float*)d_in[1];
    const int* batch  = (const int*)d_in[2];
    const float* gw1  = (const float*)d_in[4];
    const float* gb1  = (const float*)d_in[5];
    const float* gw2  = (const float*)d_in[6];
    const float* gb2  = (const float*)d_in[7];
    const float* nw1  = (const float*)d_in[8];
    const float* nb1  = (const float*)d_in[9];
    const float* nw2  = (const float*)d_in[10];
    const float* nb2  = (const float*)d_in[11];
    const float* qw1  = (const float*)d_in[12];
    const float* qb1  = (const float*)d_in[13];
    const float* qw2  = (const float*)d_in[14];
    const float* qb2  = (const float*)d_in[15];

    char* ws = (char*)d_ws;
    _Float16* q   = (_Float16*)ws;                       // 2 MB
    float* Ppre   = (float*)(ws + 2097152);              // 4 MB
    float* s      = (float*)(ws + 6291456);              // 32 KB
    _Float16* wT1 = (_Float16*)(ws + 6324224);           // 5 x 32 KB + g2h
    _Float16* wT2  = wT1 + 16384;
    _Float16* wTg  = wT2 + 16384;
    _Float16* wTq1 = wTg + 16384;
    _Float16* wTq2 = wTq1 + 16384;
    _Float16* g2h  = wTq2 + 16384;
    float* out = (float*)d_out;

    hipLaunchKernelGGL(prep_w, dim3(128), dim3(128), 0, stream,
                       nw1, nw2, gw1, gw2, qw1, qw2, wT1, wT2, wTg, wTq1, wTq2, g2h);
    hipLaunchKernelGGL(q_kernel, dim3(NB / 128), dim3(512), 0, stream,
                       u, wTq1, wTq2, qb1, qb2, q, Ppre, s);
    hipLaunchKernelGGL(hg_kernel, dim3(HG_GRID), dim3(256), 0, stream,
                       x, batch, q, wT1, wT2, wTg, g2h, nb1, nb2, gb1, gb2, Ppre, s);
    hipLaunchKernelGGL(fin_kernel, dim3(NB / 128), dim3(512), 0, stream,
                       Ppre, s, wT2, nb2, out);
}

// Round 4
// 632.472 us; speedup vs baseline: 1.4085x; 1.1733x over previous
//
#include <hip/hip_runtime.h>
#include <math.h>

#define NN 500000
#define NB 8192
#define GMAX 16
#define HG_GRID 1024
#define HG_NT ((NN + 63) / 64)

typedef _Float16 f16x8 __attribute__((ext_vector_type(8)));
typedef __fp16 fp16x2 __attribute__((ext_vector_type(2)));
typedef float f32x4 __attribute__((ext_vector_type(4)));

__device__ inline f16x8 cvt8(float4 a, float4 b) {
    union { fp16x2 p[4]; f16x8 r; } u;
    u.p[0] = __builtin_amdgcn_cvt_pkrtz(a.x, a.y);
    u.p[1] = __builtin_amdgcn_cvt_pkrtz(a.z, a.w);
    u.p[2] = __builtin_amdgcn_cvt_pkrtz(b.x, b.y);
    u.p[3] = __builtin_amdgcn_cvt_pkrtz(b.z, b.w);
    return u.r;
}

// ---------------- weight prep: W^T as f16 ----------------
__global__ void prep_w(const float* __restrict__ nw1, const float* __restrict__ nw2,
                       const float* __restrict__ gw1, const float* __restrict__ gw2,
                       const float* __restrict__ qw1, const float* __restrict__ qw2,
                       _Float16* __restrict__ wT1, _Float16* __restrict__ wT2,
                       _Float16* __restrict__ wTg, _Float16* __restrict__ wTq1,
                       _Float16* __restrict__ wTq2, _Float16* __restrict__ g2h) {
    int k = blockIdx.x;   // input dim
    int n = threadIdx.x;  // output dim
    wT1[n * 128 + k]  = (_Float16)nw1[k * 128 + n];
    wT2[n * 128 + k]  = (_Float16)nw2[k * 128 + n];
    wTg[n * 128 + k]  = (_Float16)gw1[k * 128 + n];
    wTq1[n * 128 + k] = (_Float16)qw1[k * 128 + n];
    wTq2[n * 128 + k] = (_Float16)qw2[k * 128 + n];
    if (k == 0) g2h[n] = (_Float16)gw2[n];
}

// ---------------- ques MLP via MFMA (q stored f16) + zero Ppre,s ----------------
__launch_bounds__(512, 4)
__global__ void q_kernel(const float* __restrict__ u,
                         const _Float16* __restrict__ wTq1, const _Float16* __restrict__ wTq2,
                         const float* __restrict__ qb1, const float* __restrict__ qb2,
                         _Float16* __restrict__ q, float* __restrict__ Ppre, float* __restrict__ s) {
    __shared__ __align__(16) _Float16 tbuf[128][136];
    const int tid  = threadIdx.x;
    const int wave = tid >> 6;
    const int lane = tid & 63;
    const int lrow = lane & 15;
    const int quad = lane >> 4;
    const int wr   = wave >> 1;
    const int wc   = wave & 1;
    const int row0 = blockIdx.x * 128;
    const int rbase = wr * 32;

    for (int idx = tid; idx < 128 * 128; idx += 512) Ppre[(size_t)row0 * 128 + idx] = 0.f;
    if (tid < 128) s[row0 + tid] = 0.f;

    f32x4 acc[2][4];
    const f32x4 fz = {0.f, 0.f, 0.f, 0.f};
#pragma unroll
    for (int mi = 0; mi < 2; ++mi)
#pragma unroll
        for (int ci = 0; ci < 4; ++ci) acc[mi][ci] = fz;

#pragma unroll
    for (int ki = 0; ki < 4; ++ki) {
        const int k = ki * 32 + quad * 8;
        f16x8 a[2];
#pragma unroll
        for (int mi = 0; mi < 2; ++mi) {
            int r = row0 + rbase + mi * 16 + lrow;
            const float4* up = (const float4*)(u + (size_t)r * 128 + k);
            a[mi] = cvt8(up[0], up[1]);
        }
        f16x8 b[4];
#pragma unroll
        for (int ci = 0; ci < 4; ++ci)
            b[ci] = *(const f16x8*)(wTq1 + (size_t)(wc * 64 + ci * 16 + lrow) * 128 + k);
#pragma unroll
        for (int mi = 0; mi < 2; ++mi)
#pragma unroll
            for (int ci = 0; ci < 4; ++ci)
                acc[mi][ci] = __builtin_amdgcn_mfma_f32_16x16x32_f16(a[mi], b[ci], acc[mi][ci], 0, 0, 0);
    }
#pragma unroll
    for (int ci = 0; ci < 4; ++ci) {
        int c = wc * 64 + ci * 16 + lrow;
        float bv = qb1[c];
#pragma unroll
        for (int mi = 0; mi < 2; ++mi)
#pragma unroll
            for (int i = 0; i < 4; ++i) {
                int r = rbase + mi * 16 + quad * 4 + i;
                tbuf[r][c] = (_Float16)fmaxf(acc[mi][ci][i] + bv, 0.f);
            }
    }
    __syncthreads();

#pragma unroll
    for (int mi = 0; mi < 2; ++mi)
#pragma unroll
        for (int ci = 0; ci < 4; ++ci) acc[mi][ci] = fz;
#pragma unroll
    for (int ki = 0; ki < 4; ++ki) {
        const int k = ki * 32 + quad * 8;
        f16x8 a[2];
#pragma unroll
        for (int mi = 0; mi < 2; ++mi)
            a[mi] = *(const f16x8*)&tbuf[rbase + mi * 16 + lrow][k];
        f16x8 b[4];
#pragma unroll
        for (int ci = 0; ci < 4; ++ci)
            b[ci] = *(const f16x8*)(wTq2 + (size_t)(wc * 64 + ci * 16 + lrow) * 128 + k);
#pragma unroll
        for (int mi = 0; mi < 2; ++mi)
#pragma unroll
            for (int ci = 0; ci < 4; ++ci)
                acc[mi][ci] = __builtin_amdgcn_mfma_f32_16x16x32_f16(a[mi], b[ci], acc[mi][ci], 0, 0, 0);
    }
#pragma unroll
    for (int ci = 0; ci < 4; ++ci) {
        int c = wc * 64 + ci * 16 + lrow;
        float bv = qb2[c];
#pragma unroll
        for (int mi = 0; mi < 2; ++mi)
#pragma unroll
            for (int i = 0; i < 4; ++i) {
                int r = row0 + rbase + mi * 16 + quad * 4 + i;
                q[(size_t)r * 128 + c] = (_Float16)(acc[mi][ci][i] + bv);
            }
    }
}

// ---------------- fused node-MLP + gate + pool-over-t1 (PERSISTENT + x prefetch) ----------------
// launch_bounds(256,2): empirically the VGPR cap is 256/waves_per_eu -> 128.
// Measured demand is ~112 (round 3: cap 84, 28 regs/thread spilled -> 237MB scratch writes).
// 128 >= 112 -> no spill. Occupancy then LDS-bound: 40448B x 4 = 158KB < 160KB -> 4 blocks/CU.
__launch_bounds__(256, 2)
__global__ void hg_kernel(const float* __restrict__ x, const int* __restrict__ batch,
                          const _Float16* __restrict__ qglob,
                          const _Float16* __restrict__ wT1, const _Float16* __restrict__ wT2,
                          const _Float16* __restrict__ wTg, const _Float16* __restrict__ g2h,
                          const float* __restrict__ nb1, const float* __restrict__ nb2,
                          const float* __restrict__ gb1, const float* __restrict__ gb2,
                          float* __restrict__ Ppre, float* __restrict__ s) {
    __shared__ __align__(16) _Float16 t1buf[64][136];    // persists: M1 out -> M2 in -> pooling B
    __shared__ __align__(16) _Float16 scratch[64][136];  // gin only
    __shared__ __align__(16) _Float16 qsE[GMAX][136];    // union: qs (f16) then E selector
    __shared__ float gpart[2][64];
    __shared__ float sacc[GMAX];
    __shared__ int batch_t[64];
    __shared__ int maxrel_sh;

    const int tid  = threadIdx.x;
    const int wave = tid >> 6;   // 0..3
    const int lane = tid & 63;
    const int lrow = lane & 15;
    const int quad = lane >> 4;
    const int wr   = wave >> 1;  // 0..1
    const int wc   = wave & 1;
    const int rbase = wr * 32;
    const int blk  = (int)blockIdx.x;

    const f32x4 fz = {0.f, 0.f, 0.f, 0.f};

    // ---- prologue: load + convert first tile; prefetch first batch window ----
    f16x8 a16[4][2];   // CURRENT tile's A fragments (f16, 32 VGPRs) — crosses loop top
    {
        const int r0 = blk * 64;
#pragma unroll
        for (int ki = 0; ki < 4; ++ki)
#pragma unroll
            for (int mi = 0; mi < 2; ++mi) {
                int r = min(r0 + rbase + mi * 16 + lrow, NN - 1);
                const float4* xp = (const float4*)(x + (size_t)r * 128 + ki * 32 + quad * 8);
                a16[ki][mi] = cvt8(xp[0], xp[1]);
            }
    }
    int bv = 0;
    if (wave == 0) {
        int i0 = blk * 64 + lane;
        bv = batch[min(i0, NN - 1)];
    }

    for (int t = blk; t < HG_NT; t += HG_GRID) {
        const int row0  = t * 64;
        const int rown0 = (t + HG_GRID) * 64;  // next tile's base (loads are row-clamped)

        // ---- setup: batch window, b_lo, maxrel (wave 0 only; uses prefetched bv) ----
        if (wave == 0) {
            batch_t[lane] = bv;
            int b0 = __shfl(bv, 0, 64);
            int rel = bv - b0;
#pragma unroll
            for (int off = 32; off >= 1; off >>= 1) rel = max(rel, __shfl_xor(rel, off, 64));
            if (lane == 0) maxrel_sh = rel;
        }
        __syncthreads();  // bar0 (also orders prev-iter qsE/t1buf reads vs this iter's writes)
        const int b_lo = batch_t[0];
        const int gcnt = min(maxrel_sh + 1, GMAX);

        // prefetch next tile's batch window (arrives during this tile's compute)
        if (wave == 0) bv = batch[min(rown0 + lane, NN - 1)];

        // qs: gather q rows for graphs in window (consumed after bar1)
        for (int idx = tid; idx < gcnt * 16; idx += 256)
            *(f16x8*)&qsE[idx >> 4][(idx & 15) * 8] =
                *(const f16x8*)(qglob + (size_t)(b_lo + (idx >> 4)) * 128 + (idx & 15) * 8);

        int grel[2][4];
#pragma unroll
        for (int mi = 0; mi < 2; ++mi)
#pragma unroll
            for (int i = 0; i < 4; ++i)
                grel[mi][i] = batch_t[rbase + mi * 16 + quad * 4 + i] - b_lo;

        f32x4 acc[2][4];
#pragma unroll
        for (int mi = 0; mi < 2; ++mi)
#pragma unroll
            for (int ci = 0; ci < 4; ++ci) acc[mi][ci] = fz;

        // ===== M1: t1 = relu(x @ w1 + b1) -> t1buf (uses a16 prepared last iter) =====
#pragma unroll
        for (int ki = 0; ki < 4; ++ki) {
            const int k = ki * 32 + quad * 8;
            f16x8 b[4];
#pragma unroll
            for (int ci = 0; ci < 4; ++ci)
                b[ci] = *(const f16x8*)(wT1 + (size_t)(wc * 64 + ci * 16 + lrow) * 128 + k);
#pragma unroll
            for (int mi = 0; mi < 2; ++mi)
#pragma unroll
                for (int ci = 0; ci < 4; ++ci)
                    acc[mi][ci] = __builtin_amdgcn_mfma_f32_16x16x32_f16(a16[ki][mi], b[ci], acc[mi][ci], 0, 0, 0);
        }
#pragma unroll
        for (int ci = 0; ci < 4; ++ci) {
            int c = wc * 64 + ci * 16 + lrow;
            float bvv = nb1[c];
#pragma unroll
            for (int mi = 0; mi < 2; ++mi)
#pragma unroll
                for (int i = 0; i < 4; ++i) {
                    int r = rbase + mi * 16 + quad * 4 + i;
                    t1buf[r][c] = (_Float16)fmaxf(acc[mi][ci][i] + bvv, 0.f);
                }
        }
        __syncthreads();  // bar1: t1 + qs visible

        // ---- issue next tile's x loads NOW (xraw live only bar1 -> bar2) ----
        float4 xraw[4][2][2];
#pragma unroll
        for (int ki = 0; ki < 4; ++ki)
#pragma unroll
            for (int mi = 0; mi < 2; ++mi) {
                int r = min(rown0 + rbase + mi * 16 + lrow, NN - 1);
                const float4* xp = (const float4*)(x + (size_t)r * 128 + ki * 32 + quad * 8);
                xraw[ki][mi][0] = xp[0];
                xraw[ki][mi][1] = xp[1];
            }

        // ===== M2: h = t1 @ w2 + b2 ; gin = q[batch] * h -> scratch =====
#pragma unroll
        for (int mi = 0; mi < 2; ++mi)
#pragma unroll
            for (int ci = 0; ci < 4; ++ci) acc[mi][ci] = fz;
#pragma unroll
        for (int ki = 0; ki < 4; ++ki) {
            const int k = ki * 32 + quad * 8;
            f16x8 a[2];
#pragma unroll
            for (int mi = 0; mi < 2; ++mi)
                a[mi] = *(const f16x8*)&t1buf[rbase + mi * 16 + lrow][k];
            f16x8 b[4];
#pragma unroll
            for (int ci = 0; ci < 4; ++ci)
                b[ci] = *(const f16x8*)(wT2 + (size_t)(wc * 64 + ci * 16 + lrow) * 128 + k);
#pragma unroll
            for (int mi = 0; mi < 2; ++mi)
#pragma unroll
                for (int ci = 0; ci < 4; ++ci)
                    acc[mi][ci] = __builtin_amdgcn_mfma_f32_16x16x32_f16(a[mi], b[ci], acc[mi][ci], 0, 0, 0);
        }
#pragma unroll
        for (int ci = 0; ci < 4; ++ci) {
            int c = wc * 64 + ci * 16 + lrow;
            float bvv = nb2[c];
#pragma unroll
            for (int mi = 0; mi < 2; ++mi)
#pragma unroll
                for (int i = 0; i < 4; ++i) {
                    int r = rbase + mi * 16 + quad * 4 + i;
                    float h = acc[mi][ci][i] + bvv;
                    int g = grel[mi][i];
                    float qv = (g < GMAX) ? (float)qsE[g][c]
                                          : (float)qglob[(size_t)(b_lo + g) * 128 + c];
                    scratch[r][c] = (_Float16)(qv * h);
                }
        }
        __syncthreads();  // bar2: gin visible, qs reads done (implicit vmcnt(0): xraw complete)

        // convert next tile's x to f16 NOW — frees the 64 f32 prefetch regs before M3
        #pragma unroll
        for (int ki = 0; ki < 4; ++ki)
#pragma unroll
            for (int mi = 0; mi < 2; ++mi)
                a16[ki][mi] = cvt8(xraw[ki][mi][0], xraw[ki][mi][1]);

        // zero E + sacc (visible after bar3)
        for (int idx = tid; idx < GMAX * 136 / 2; idx += 256) ((float*)qsE)[idx] = 0.f;
        if (tid < GMAX) sacc[tid] = 0.f;

        // ===== M3: t2 = relu(gin @ gw1 + gb1); gate partial via gw2 dot + shuffle =====
#pragma unroll
        for (int mi = 0; mi < 2; ++mi)
#pragma unroll
            for (int ci = 0; ci < 4; ++ci) acc[mi][ci] = fz;
        float g2hreg[4];
#pragma unroll
        for (int ci = 0; ci < 4; ++ci) g2hreg[ci] = (float)g2h[wc * 64 + ci * 16 + lrow];
#pragma unroll
        for (int ki = 0; ki < 4; ++ki) {
            const int k = ki * 32 + quad * 8;
            f16x8 a[2];
#pragma unroll
            for (int mi = 0; mi < 2; ++mi)
                a[mi] = *(const f16x8*)&scratch[rbase + mi * 16 + lrow][k];
            f16x8 b[4];
#pragma unroll
            for (int ci = 0; ci < 4; ++ci)
                b[ci] = *(const f16x8*)(wTg + (size_t)(wc * 64 + ci * 16 + lrow) * 128 + k);
#pragma unroll
            for (int mi = 0; mi < 2; ++mi)
#pragma unroll
                for (int ci = 0; ci < 4; ++ci)
                    acc[mi][ci] = __builtin_amdgcn_mfma_f32_16x16x32_f16(a[mi], b[ci], acc[mi][ci], 0, 0, 0);
        }
        float p[2][4] = {{0.f, 0.f, 0.f, 0.f}, {0.f, 0.f, 0.f, 0.f}};
#pragma unroll
        for (int ci = 0; ci < 4; ++ci) {
            int c = wc * 64 + ci * 16 + lrow;
            float bvv = gb1[c];
            float w = g2hreg[ci];
#pragma unroll
            for (int mi = 0; mi < 2; ++mi)
#pragma unroll
                for (int i = 0; i < 4; ++i)
                    p[mi][i] = fmaf(fmaxf(acc[mi][ci][i] + bvv, 0.f), w, p[mi][i]);
        }
#pragma unroll
        for (int off = 1; off <= 8; off <<= 1)
#pragma unroll
            for (int mi = 0; mi < 2; ++mi)
#pragma unroll
                for (int i = 0; i < 4; ++i)
                    p[mi][i] += __shfl_xor(p[mi][i], off, 64);
        if (lrow == 0) {
#pragma unroll
            for (int mi = 0; mi < 2; ++mi)
#pragma unroll
                for (int i = 0; i < 4; ++i)
                    gpart[wc][rbase + mi * 16 + quad * 4 + i] = p[mi][i];
        }
        __syncthreads();  // bar3: gpart + E-zero visible

        // ===== gate -> e -> E selector (one thread per row) =====
        const float gb2v = gb2[0];
        if (tid < 64) {
            int r = tid;
            int g = batch_t[r] - b_lo;
            bool valid = (row0 + r) < NN;
            float e = valid ? __expf(gpart[0][r] + gpart[1][r] + gb2v) : 0.f;
            if (g < GMAX) {
                qsE[g][r] = (_Float16)e;
                atomicAdd(&sacc[g], e);
            } else if (valid) {  // pathological >16 graphs per 64-row window
                atomicAdd(&s[b_lo + g], e);
                for (int c = 0; c < 128; ++c)
                    atomicAdd(&Ppre[(size_t)(b_lo + g) * 128 + c], e * (float)t1buf[r][c]);
            }
        }
        __syncthreads();  // bar4: E visible

        // ===== pooling: Ppre_tile = E(16x64) @ T1(64x128), each wave 32 cols =====
        f16x8 aE[2];
#pragma unroll
        for (int ki = 0; ki < 2; ++ki)
            aE[ki] = *(const f16x8*)&qsE[lrow][ki * 32 + quad * 8];
        f32x4 pacc[2] = {fz, fz};
#pragma unroll
        for (int ci2 = 0; ci2 < 2; ++ci2) {
            int col = wave * 32 + ci2 * 16 + lrow;
#pragma unroll
            for (int ki = 0; ki < 2; ++ki) {
                f16x8 bh;
#pragma unroll
                for (int j = 0; j < 8; ++j) bh[j] = t1buf[ki * 32 + quad * 8 + j][col];
                pacc[ci2] = __builtin_amdgcn_mfma_f32_16x16x32_f16(aE[ki], bh, pacc[ci2], 0, 0, 0);
            }
        }
#pragma unroll
        for (int ci2 = 0; ci2 < 2; ++ci2)
#pragma unroll
            for (int i = 0; i < 4; ++i) {
                int g = quad * 4 + i;
                if (g < gcnt)
                    atomicAdd(&Ppre[(size_t)(b_lo + g) * 128 + wave * 32 + ci2 * 16 + lrow], pacc[ci2][i]);
            }
        if (tid < gcnt) atomicAdd(&s[b_lo + tid], sacc[tid]);
    }
}

// ---------------- finalize: out = (Ppre @ w2 + s*b2) / (s + eps) ----------------
__launch_bounds__(512, 4)
__global__ void fin_kernel(const float* __restrict__ Ppre, const float* __restrict__ s,
                           const _Float16* __restrict__ wT2, const float* __restrict__ nb2,
                           float* __restrict__ out) {
    const int tid  = threadIdx.x;
    const int wave = tid >> 6;
    const int lane = tid & 63;
    const int lrow = lane & 15;
    const int quad = lane >> 4;
    const int wr   = wave >> 1;
    const int wc   = wave & 1;
    const int row0 = blockIdx.x * 128;
    const int rbase = wr * 32;

    f32x4 acc[2][4];
    const f32x4 fz = {0.f, 0.f, 0.f, 0.f};
#pragma unroll
    for (int mi = 0; mi < 2; ++mi)
#pragma unroll
        for (int ci = 0; ci < 4; ++ci) acc[mi][ci] = fz;
#pragma unroll
    for (int ki = 0; ki < 4; ++ki) {
        const int k = ki * 32 + quad * 8;
        f16x8 a[2];
#pragma unroll
        for (int mi = 0; mi < 2; ++mi) {
            int r = row0 + rbase + mi * 16 + lrow;
            const float4* pp = (const float4*)(Ppre + (size_t)r * 128 + k);
            a[mi] = cvt8(pp[0], pp[1]);
        }
        f16x8 b[4];
#pragma unroll
        for (int ci = 0; ci < 4; ++ci)
            b[ci] = *(const f16x8*)(wT2 + (size_t)(wc * 64 + ci * 16 + lrow) * 128 + k);
#pragma unroll
        for (int mi = 0; mi < 2; ++mi)
#pragma unroll
            for (int ci = 0; ci < 4; ++ci)
                acc[mi][ci] = __builtin_amdgcn_mfma_f32_16x16x32_f16(a[mi], b[ci], acc[mi][ci], 0, 0, 0);
    }
    float sv[2][4], rinv[2][4];
#pragma unroll
    for (int mi = 0; mi < 2; ++mi)
#pragma unroll
        for (int i = 0; i < 4; ++i) {
            int r = row0 + rbase + mi * 16 + quad * 4 + i;
            sv[mi][i] = s[r];
            rinv[mi][i] = 1.f / (sv[mi][i] + 1e-16f);
        }
#pragma unroll
    for (int ci = 0; ci < 4; ++ci) {
        int c = wc * 64 + ci * 16 + lrow;
        float bv = nb2[c];
#pragma unroll
        for (int mi = 0; mi < 2; ++mi)
#pragma unroll
            for (int i = 0; i < 4; ++i) {
                int r = row0 + rbase + mi * 16 + quad * 4 + i;
                out[(size_t)r * 128 + c] = (acc[mi][ci][i] + sv[mi][i] * bv) * rinv[mi][i];
            }
    }
}

extern "C" void kernel_launch(void* const* d_in, const int* in_sizes, int n_in,
                              void* d_out, int out_size, void* d_ws, size_t ws_size,
                              hipStream_t stream) {
    const float* x    = (const float*)d_in[0];
    const float* u    = (const float*)d_in[1];
    const int* batch  = (const int*)d_in[2];
    const float* gw1  = (const float*)d_in[4];
    const float* gb1  = (const float*)d_in[5];
    const float* gw2  = (const float*)d_in[6];
    const float* gb2  = (const float*)d_in[7];
    const float* nw1  = (const float*)d_in[8];
    const float* nb1  = (const float*)d_in[9];
    const float* nw2  = (const float*)d_in[10];
    const float* nb2  = (const float*)d_in[11];
    const float* qw1  = (const float*)d_in[12];
    const float* qb1  = (const float*)d_in[13];
    const float* qw2  = (const float*)d_in[14];
    const float* qb2  = (const float*)d_in[15];

    char* ws = (char*)d_ws;
    _Float16* q   = (_Float16*)ws;                       // 2 MB
    float* Ppre   = (float*)(ws + 2097152);              // 4 MB
    float* s      = (float*)(ws + 6291456);              // 32 KB
    _Float16* wT1 = (_Float16*)(ws + 6324224);           // 5 x 32 KB + g2h
    _Float16* wT2  = wT1 + 16384;
    _Float16* wTg  = wT2 + 16384;
    _Float16* wTq1 = wTg + 16384;
    _Float16* wTq2 = wTq1 + 16384;
    _Float16* g2h  = wTq2 + 16384;
    float* out = (float*)d_out;

    hipLaunchKernelGGL(prep_w, dim3(128), dim3(128), 0, stream,
                       nw1, nw2, gw1, gw2, qw1, qw2, wT1, wT2, wTg, wTq1, wTq2, g2h);
    hipLaunchKernelGGL(q_kernel, dim3(NB / 128), dim3(512), 0, stream,
                       u, wTq1, wTq2, qb1, qb2, q, Ppre, s);
    hipLaunchKernelGGL(hg_kernel, dim3(HG_GRID), dim3(256), 0, stream,
                       x, batch, q, wT1, wT2, wTg, g2h, nb1, nb2, gb1, gb2, Ppre, s);
    hipLaunchKernelGGL(fin_kernel, dim3(NB / 128), dim3(512), 0, stream,
                       Ppre, s, wT2, nb2, out);
}

// Round 5
// 604.649 us; speedup vs baseline: 1.4733x; 1.0460x over previous
//
#include <hip/hip_runtime.h>
#include <math.h>

#define NN 500000
#define NB 8192
#define GMAX 16
#define HG_GRID 1024
#define HG_NT ((NN + 63) / 64)

typedef _Float16 f16x8 __attribute__((ext_vector_type(8)));
typedef __fp16 fp16x2 __attribute__((ext_vector_type(2)));
typedef float f32x4 __attribute__((ext_vector_type(4)));

__device__ inline f16x8 cvt8(float4 a, float4 b) {
    union { fp16x2 p[4]; f16x8 r; } u;
    u.p[0] = __builtin_amdgcn_cvt_pkrtz(a.x, a.y);
    u.p[1] = __builtin_amdgcn_cvt_pkrtz(a.z, a.w);
    u.p[2] = __builtin_amdgcn_cvt_pkrtz(b.x, b.y);
    u.p[3] = __builtin_amdgcn_cvt_pkrtz(b.z, b.w);
    return u.r;
}

// ---------------- weight prep: W^T as f16 ----------------
__global__ void prep_w(const float* __restrict__ nw1, const float* __restrict__ nw2,
                       const float* __restrict__ gw1, const float* __restrict__ gw2,
                       const float* __restrict__ qw1, const float* __restrict__ qw2,
                       _Float16* __restrict__ wT1, _Float16* __restrict__ wT2,
                       _Float16* __restrict__ wTg, _Float16* __restrict__ wTq1,
                       _Float16* __restrict__ wTq2, _Float16* __restrict__ g2h) {
    int k = blockIdx.x;   // input dim
    int n = threadIdx.x;  // output dim
    wT1[n * 128 + k]  = (_Float16)nw1[k * 128 + n];
    wT2[n * 128 + k]  = (_Float16)nw2[k * 128 + n];
    wTg[n * 128 + k]  = (_Float16)gw1[k * 128 + n];
    wTq1[n * 128 + k] = (_Float16)qw1[k * 128 + n];
    wTq2[n * 128 + k] = (_Float16)qw2[k * 128 + n];
    if (k == 0) g2h[n] = (_Float16)gw2[n];
}

// ---------------- ques MLP via MFMA (q stored f16) + zero Ppre,s ----------------
__launch_bounds__(512, 4)
__global__ void q_kernel(const float* __restrict__ u,
                         const _Float16* __restrict__ wTq1, const _Float16* __restrict__ wTq2,
                         const float* __restrict__ qb1, const float* __restrict__ qb2,
                         _Float16* __restrict__ q, float* __restrict__ Ppre, float* __restrict__ s) {
    __shared__ __align__(16) _Float16 tbuf[128][136];
    const int tid  = threadIdx.x;
    const int wave = tid >> 6;
    const int lane = tid & 63;
    const int lrow = lane & 15;
    const int quad = lane >> 4;
    const int wr   = wave >> 1;
    const int wc   = wave & 1;
    const int row0 = blockIdx.x * 128;
    const int rbase = wr * 32;

    for (int idx = tid; idx < 128 * 128; idx += 512) Ppre[(size_t)row0 * 128 + idx] = 0.f;
    if (tid < 128) s[row0 + tid] = 0.f;

    f32x4 acc[2][4];
    const f32x4 fz = {0.f, 0.f, 0.f, 0.f};
#pragma unroll
    for (int mi = 0; mi < 2; ++mi)
#pragma unroll
        for (int ci = 0; ci < 4; ++ci) acc[mi][ci] = fz;

#pragma unroll
    for (int ki = 0; ki < 4; ++ki) {
        const int k = ki * 32 + quad * 8;
        f16x8 a[2];
#pragma unroll
        for (int mi = 0; mi < 2; ++mi) {
            int r = row0 + rbase + mi * 16 + lrow;
            const float4* up = (const float4*)(u + (size_t)r * 128 + k);
            a[mi] = cvt8(up[0], up[1]);
        }
        f16x8 b[4];
#pragma unroll
        for (int ci = 0; ci < 4; ++ci)
            b[ci] = *(const f16x8*)(wTq1 + (size_t)(wc * 64 + ci * 16 + lrow) * 128 + k);
#pragma unroll
        for (int mi = 0; mi < 2; ++mi)
#pragma unroll
            for (int ci = 0; ci < 4; ++ci)
                acc[mi][ci] = __builtin_amdgcn_mfma_f32_16x16x32_f16(a[mi], b[ci], acc[mi][ci], 0, 0, 0);
    }
#pragma unroll
    for (int ci = 0; ci < 4; ++ci) {
        int c = wc * 64 + ci * 16 + lrow;
        float bv = qb1[c];
#pragma unroll
        for (int mi = 0; mi < 2; ++mi)
#pragma unroll
            for (int i = 0; i < 4; ++i) {
                int r = rbase + mi * 16 + quad * 4 + i;
                tbuf[r][c] = (_Float16)fmaxf(acc[mi][ci][i] + bv, 0.f);
            }
    }
    __syncthreads();

#pragma unroll
    for (int mi = 0; mi < 2; ++mi)
#pragma unroll
        for (int ci = 0; ci < 4; ++ci) acc[mi][ci] = fz;
#pragma unroll
    for (int ki = 0; ki < 4; ++ki) {
        const int k = ki * 32 + quad * 8;
        f16x8 a[2];
#pragma unroll
        for (int mi = 0; mi < 2; ++mi)
            a[mi] = *(const f16x8*)&tbuf[rbase + mi * 16 + lrow][k];
        f16x8 b[4];
#pragma unroll
        for (int ci = 0; ci < 4; ++ci)
            b[ci] = *(const f16x8*)(wTq2 + (size_t)(wc * 64 + ci * 16 + lrow) * 128 + k);
#pragma unroll
        for (int mi = 0; mi < 2; ++mi)
#pragma unroll
            for (int ci = 0; ci < 4; ++ci)
                acc[mi][ci] = __builtin_amdgcn_mfma_f32_16x16x32_f16(a[mi], b[ci], acc[mi][ci], 0, 0, 0);
    }
#pragma unroll
    for (int ci = 0; ci < 4; ++ci) {
        int c = wc * 64 + ci * 16 + lrow;
        float bv = qb2[c];
#pragma unroll
        for (int mi = 0; mi < 2; ++mi)
#pragma unroll
            for (int i = 0; i < 4; ++i) {
                int r = row0 + rbase + mi * 16 + quad * 4 + i;
                q[(size_t)r * 128 + c] = (_Float16)(acc[mi][ci][i] + bv);
            }
    }
}

// ---------------- fused node-MLP + gate + pool-over-t1 (PERSISTENT + split x prefetch) ----------------
// (256,2): VGPR cap 128. Round-4 demand was ~145 (17 regs spilled at cap 128 -> 144MB scratch
// writes). This version cuts peak demand below the cap: x prefetch split into two 32-reg
// chunks with disjoint live ranges (A: bar1->bar2, B: post-M3->pool-end), grel recomputed at
// use. sched_barrier(0) before each issue point stops the scheduler hoisting the loads into
// the previous high-pressure region.
__launch_bounds__(256, 2)
__global__ void hg_kernel(const float* __restrict__ x, const int* __restrict__ batch,
                          const _Float16* __restrict__ qglob,
                          const _Float16* __restrict__ wT1, const _Float16* __restrict__ wT2,
                          const _Float16* __restrict__ wTg, const _Float16* __restrict__ g2h,
                          const float* __restrict__ nb1, const float* __restrict__ nb2,
                          const float* __restrict__ gb1, const float* __restrict__ gb2,
                          float* __restrict__ Ppre, float* __restrict__ s) {
    __shared__ __align__(16) _Float16 t1buf[64][136];    // persists: M1 out -> M2 in -> pooling B
    __shared__ __align__(16) _Float16 scratch[64][136];  // gin only
    __shared__ __align__(16) _Float16 qsE[GMAX][136];    // union: qs (f16) then E selector
    __shared__ float gpart[2][64];
    __shared__ float sacc[GMAX];
    __shared__ int batch_t[64];
    __shared__ int maxrel_sh;

    const int tid  = threadIdx.x;
    const int wave = tid >> 6;   // 0..3
    const int lane = tid & 63;
    const int lrow = lane & 15;
    const int quad = lane >> 4;
    const int wr   = wave >> 1;  // 0..1
    const int wc   = wave & 1;
    const int rbase = wr * 32;
    const int blk  = (int)blockIdx.x;

    const f32x4 fz = {0.f, 0.f, 0.f, 0.f};

    // ---- prologue: load + convert first tile; prefetch first batch window ----
    f16x8 a16[4][2];   // CURRENT tile's A fragments (f16, 32 VGPRs) — crosses loop top
    {
        const int r0 = blk * 64;
#pragma unroll
        for (int ki = 0; ki < 4; ++ki)
#pragma unroll
            for (int mi = 0; mi < 2; ++mi) {
                int r = min(r0 + rbase + mi * 16 + lrow, NN - 1);
                const float4* xp = (const float4*)(x + (size_t)r * 128 + ki * 32 + quad * 8);
                a16[ki][mi] = cvt8(xp[0], xp[1]);
            }
    }
    int bv = 0;
    if (wave == 0) {
        int i0 = blk * 64 + lane;
        bv = batch[min(i0, NN - 1)];
    }

    for (int t = blk; t < HG_NT; t += HG_GRID) {
        const int row0  = t * 64;
        const int rown0 = (t + HG_GRID) * 64;  // next tile's base (loads are row-clamped)

        // ---- setup: batch window, b_lo, maxrel (wave 0 only; uses prefetched bv) ----
        if (wave == 0) {
            batch_t[lane] = bv;
            int b0 = __shfl(bv, 0, 64);
            int rel = bv - b0;
#pragma unroll
            for (int off = 32; off >= 1; off >>= 1) rel = max(rel, __shfl_xor(rel, off, 64));
            if (lane == 0) maxrel_sh = rel;
        }
        __syncthreads();  // bar0 (also orders prev-iter qsE/t1buf reads vs this iter's writes)
        const int b_lo = batch_t[0];
        const int gcnt = min(maxrel_sh + 1, GMAX);

        // prefetch next tile's batch window (arrives during this tile's compute)
        if (wave == 0) bv = batch[min(rown0 + lane, NN - 1)];

        // qs: gather q rows for graphs in window (consumed after bar1)
        for (int idx = tid; idx < gcnt * 16; idx += 256)
            *(f16x8*)&qsE[idx >> 4][(idx & 15) * 8] =
                *(const f16x8*)(qglob + (size_t)(b_lo + (idx >> 4)) * 128 + (idx & 15) * 8);

        f32x4 acc[2][4];
#pragma unroll
        for (int mi = 0; mi < 2; ++mi)
#pragma unroll
            for (int ci = 0; ci < 4; ++ci) acc[mi][ci] = fz;

        // ===== M1: t1 = relu(x @ w1 + b1) -> t1buf (uses a16 prepared last iter) =====
#pragma unroll
        for (int ki = 0; ki < 4; ++ki) {
            const int k = ki * 32 + quad * 8;
            f16x8 b[4];
#pragma unroll
            for (int ci = 0; ci < 4; ++ci)
                b[ci] = *(const f16x8*)(wT1 + (size_t)(wc * 64 + ci * 16 + lrow) * 128 + k);
#pragma unroll
            for (int mi = 0; mi < 2; ++mi)
#pragma unroll
                for (int ci = 0; ci < 4; ++ci)
                    acc[mi][ci] = __builtin_amdgcn_mfma_f32_16x16x32_f16(a16[ki][mi], b[ci], acc[mi][ci], 0, 0, 0);
        }
#pragma unroll
        for (int ci = 0; ci < 4; ++ci) {
            int c = wc * 64 + ci * 16 + lrow;
            float bvv = nb1[c];
#pragma unroll
            for (int mi = 0; mi < 2; ++mi)
#pragma unroll
                for (int i = 0; i < 4; ++i) {
                    int r = rbase + mi * 16 + quad * 4 + i;
                    t1buf[r][c] = (_Float16)fmaxf(acc[mi][ci][i] + bvv, 0.f);
                }
        }
        __syncthreads();  // bar1: t1 + qs visible

        // ---- issue chunk A of next tile's x (ki=0,1; 32 f32 regs, live bar1->bar2) ----
        __builtin_amdgcn_sched_barrier(0);
        float4 xrawA[2][2][2];
#pragma unroll
        for (int ki = 0; ki < 2; ++ki)
#pragma unroll
            for (int mi = 0; mi < 2; ++mi) {
                int r = min(rown0 + rbase + mi * 16 + lrow, NN - 1);
                const float4* xp = (const float4*)(x + (size_t)r * 128 + ki * 32 + quad * 8);
                xrawA[ki][mi][0] = xp[0];
                xrawA[ki][mi][1] = xp[1];
            }

        // ===== M2: h = t1 @ w2 + b2 ; gin = q[batch] * h -> scratch =====
#pragma unroll
        for (int mi = 0; mi < 2; ++mi)
#pragma unroll
            for (int ci = 0; ci < 4; ++ci) acc[mi][ci] = fz;
#pragma unroll
        for (int ki = 0; ki < 4; ++ki) {
            const int k = ki * 32 + quad * 8;
            f16x8 a[2];
#pragma unroll
            for (int mi = 0; mi < 2; ++mi)
                a[mi] = *(const f16x8*)&t1buf[rbase + mi * 16 + lrow][k];
            f16x8 b[4];
#pragma unroll
            for (int ci = 0; ci < 4; ++ci)
                b[ci] = *(const f16x8*)(wT2 + (size_t)(wc * 64 + ci * 16 + lrow) * 128 + k);
#pragma unroll
            for (int mi = 0; mi < 2; ++mi)
#pragma unroll
                for (int ci = 0; ci < 4; ++ci)
                    acc[mi][ci] = __builtin_amdgcn_mfma_f32_16x16x32_f16(a[mi], b[ci], acc[mi][ci], 0, 0, 0);
        }
#pragma unroll
        for (int ci = 0; ci < 4; ++ci) {
            int c = wc * 64 + ci * 16 + lrow;
            float bvv = nb2[c];
#pragma unroll
            for (int mi = 0; mi < 2; ++mi)
#pragma unroll
                for (int i = 0; i < 4; ++i) {
                    int r = rbase + mi * 16 + quad * 4 + i;
                    float h = acc[mi][ci][i] + bvv;
                    int g = batch_t[r] - b_lo;  // recomputed at use (saves 8 live regs)
                    float qv = (g < GMAX) ? (float)qsE[g][c]
                                          : (float)qglob[(size_t)(b_lo + g) * 128 + c];
                    scratch[r][c] = (_Float16)(qv * h);
                }
        }
        __syncthreads();  // bar2: gin visible, qs reads done

        // convert chunk A now (vmcnt wait covered by M2's MFMAs); frees xrawA regs
#pragma unroll
        for (int ki = 0; ki < 2; ++ki)
#pragma unroll
            for (int mi = 0; mi < 2; ++mi)
                a16[ki][mi] = cvt8(xrawA[ki][mi][0], xrawA[ki][mi][1]);

        // zero E + sacc (visible after bar3)
        for (int idx = tid; idx < GMAX * 136 / 2; idx += 256) ((float*)qsE)[idx] = 0.f;
        if (tid < GMAX) sacc[tid] = 0.f;

        // ===== M3: t2 = relu(gin @ gw1 + gb1); gate partial via gw2 dot + shuffle =====
#pragma unroll
        for (int mi = 0; mi < 2; ++mi)
#pragma unroll
            for (int ci = 0; ci < 4; ++ci) acc[mi][ci] = fz;
        float g2hreg[4];
#pragma unroll
        for (int ci = 0; ci < 4; ++ci) g2hreg[ci] = (float)g2h[wc * 64 + ci * 16 + lrow];
#pragma unroll
        for (int ki = 0; ki < 4; ++ki) {
            const int k = ki * 32 + quad * 8;
            f16x8 a[2];
#pragma unroll
            for (int mi = 0; mi < 2; ++mi)
                a[mi] = *(const f16x8*)&scratch[rbase + mi * 16 + lrow][k];
            f16x8 b[4];
#pragma unroll
            for (int ci = 0; ci < 4; ++ci)
                b[ci] = *(const f16x8*)(wTg + (size_t)(wc * 64 + ci * 16 + lrow) * 128 + k);
#pragma unroll
            for (int mi = 0; mi < 2; ++mi)
#pragma unroll
                for (int ci = 0; ci < 4; ++ci)
                    acc[mi][ci] = __builtin_amdgcn_mfma_f32_16x16x32_f16(a[mi], b[ci], acc[mi][ci], 0, 0, 0);
        }

        // ---- issue chunk B of next tile's x (ki=2,3; live M3-epilogue -> pool end) ----
        __builtin_amdgcn_sched_barrier(0);
        float4 xrawB[2][2][2];
#pragma unroll
        for (int ki = 0; ki < 2; ++ki)
#pragma unroll
            for (int mi = 0; mi < 2; ++mi) {
                int r = min(rown0 + rbase + mi * 16 + lrow, NN - 1);
                const float4* xp = (const float4*)(x + (size_t)r * 128 + (ki + 2) * 32 + quad * 8);
                xrawB[ki][mi][0] = xp[0];
                xrawB[ki][mi][1] = xp[1];
            }

        float p[2][4] = {{0.f, 0.f, 0.f, 0.f}, {0.f, 0.f, 0.f, 0.f}};
#pragma unroll
        for (int ci = 0; ci < 4; ++ci) {
            int c = wc * 64 + ci * 16 + lrow;
            float bvv = gb1[c];
            float w = g2hreg[ci];
#pragma unroll
            for (int mi = 0; mi < 2; ++mi)
#pragma unroll
                for (int i = 0; i < 4; ++i)
                    p[mi][i] = fmaf(fmaxf(acc[mi][ci][i] + bvv, 0.f), w, p[mi][i]);
        }
#pragma unroll
        for (int off = 1; off <= 8; off <<= 1)
#pragma unroll
            for (int mi = 0; mi < 2; ++mi)
#pragma unroll
                for (int i = 0; i < 4; ++i)
                    p[mi][i] += __shfl_xor(p[mi][i], off, 64);
        if (lrow == 0) {
#pragma unroll
            for (int mi = 0; mi < 2; ++mi)
#pragma unroll
                for (int i = 0; i < 4; ++i)
                    gpart[wc][rbase + mi * 16 + quad * 4 + i] = p[mi][i];
        }
        __syncthreads();  // bar3: gpart + E-zero visible

        // ===== gate -> e -> E selector (one thread per row) =====
        const float gb2v = gb2[0];
        if (tid < 64) {
            int r = tid;
            int g = batch_t[r] - b_lo;
            bool valid = (row0 + r) < NN;
            float e = valid ? __expf(gpart[0][r] + gpart[1][r] + gb2v) : 0.f;
            if (g < GMAX) {
                qsE[g][r] = (_Float16)e;
                atomicAdd(&sacc[g], e);
            } else if (valid) {  // pathological >16 graphs per 64-row window
                atomicAdd(&s[b_lo + g], e);
                for (int c = 0; c < 128; ++c)
                    atomicAdd(&Ppre[(size_t)(b_lo + g) * 128 + c], e * (float)t1buf[r][c]);
            }
        }
        __syncthreads();  // bar4: E visible

        // ===== pooling: Ppre_tile = E(16x64) @ T1(64x128), each wave 32 cols =====
        f16x8 aE[2];
#pragma unroll
        for (int ki = 0; ki < 2; ++ki)
            aE[ki] = *(const f16x8*)&qsE[lrow][ki * 32 + quad * 8];
        f32x4 pacc[2] = {fz, fz};
#pragma unroll
        for (int ci2 = 0; ci2 < 2; ++ci2) {
            int col = wave * 32 + ci2 * 16 + lrow;
#pragma unroll
            for (int ki = 0; ki < 2; ++ki) {
                f16x8 bh;
#pragma unroll
                for (int j = 0; j < 8; ++j) bh[j] = t1buf[ki * 32 + quad * 8 + j][col];
                pacc[ci2] = __builtin_amdgcn_mfma_f32_16x16x32_f16(aE[ki], bh, pacc[ci2], 0, 0, 0);
            }
        }
#pragma unroll
        for (int ci2 = 0; ci2 < 2; ++ci2)
#pragma unroll
            for (int i = 0; i < 4; ++i) {
                int g = quad * 4 + i;
                if (g < gcnt)
                    atomicAdd(&Ppre[(size_t)(b_lo + g) * 128 + wave * 32 + ci2 * 16 + lrow], pacc[ci2][i]);
            }

        // convert chunk B (loads long since landed; frees xrawB before next iter)
#pragma unroll
        for (int ki = 0; ki < 2; ++ki)
#pragma unroll
            for (int mi = 0; mi < 2; ++mi)
                a16[ki + 2][mi] = cvt8(xrawB[ki][mi][0], xrawB[ki][mi][1]);

        if (tid < gcnt) atomicAdd(&s[b_lo + tid], sacc[tid]);
    }
}

// ---------------- finalize: out = (Ppre @ w2 + s*b2) / (s + eps) ----------------
__launch_bounds__(512, 4)
__global__ void fin_kernel(const float* __restrict__ Ppre, const float* __restrict__ s,
                           const _Float16* __restrict__ wT2, const float* __restrict__ nb2,
                           float* __restrict__ out) {
    const int tid  = threadIdx.x;
    const int wave = tid >> 6;
    const int lane = tid & 63;
    const int lrow = lane & 15;
    const int quad = lane >> 4;
    const int wr   = wave >> 1;
    const int wc   = wave & 1;
    const int row0 = blockIdx.x * 128;
    const int rbase = wr * 32;

    f32x4 acc[2][4];
    const f32x4 fz = {0.f, 0.f, 0.f, 0.f};
#pragma unroll
    for (int mi = 0; mi < 2; ++mi)
#pragma unroll
        for (int ci = 0; ci < 4; ++ci) acc[mi][ci] = fz;
#pragma unroll
    for (int ki = 0; ki < 4; ++ki) {
        const int k = ki * 32 + quad * 8;
        f16x8 a[2];
#pragma unroll
        for (int mi = 0; mi < 2; ++mi) {
            int r = row0 + rbase + mi * 16 + lrow;
            const float4* pp = (const float4*)(Ppre + (size_t)r * 128 + k);
            a[mi] = cvt8(pp[0], pp[1]);
        }
        f16x8 b[4];
#pragma unroll
        for (int ci = 0; ci < 4; ++ci)
            b[ci] = *(const f16x8*)(wT2 + (size_t)(wc * 64 + ci * 16 + lrow) * 128 + k);
#pragma unroll
        for (int mi = 0; mi < 2; ++mi)
#pragma unroll
            for (int ci = 0; ci < 4; ++ci)
                acc[mi][ci] = __builtin_amdgcn_mfma_f32_16x16x32_f16(a[mi], b[ci], acc[mi][ci], 0, 0, 0);
    }
    float sv[2][4], rinv[2][4];
#pragma unroll
    for (int mi = 0; mi < 2; ++mi)
#pragma unroll
        for (int i = 0; i < 4; ++i) {
            int r = row0 + rbase + mi * 16 + quad * 4 + i;
            sv[mi][i] = s[r];
            rinv[mi][i] = 1.f / (sv[mi][i] + 1e-16f);
        }
#pragma unroll
    for (int ci = 0; ci < 4; ++ci) {
        int c = wc * 64 + ci * 16 + lrow;
        float bv = nb2[c];
#pragma unroll
        for (int mi = 0; mi < 2; ++mi)
#pragma unroll
            for (int i = 0; i < 4; ++i) {
                int r = row0 + rbase + mi * 16 + quad * 4 + i;
                out[(size_t)r * 128 + c] = (acc[mi][ci][i] + sv[mi][i] * bv) * rinv[mi][i];
            }
    }
}

extern "C" void kernel_launch(void* const* d_in, const int* in_sizes, int n_in,
                              void* d_out, int out_size, void* d_ws, size_t ws_size,
                              hipStream_t stream) {
    const float* x    = (const float*)d_in[0];
    const float* u    = (const float*)d_in[1];
    const int* batch  = (const int*)d_in[2];
    const float* gw1  = (const float*)d_in[4];
    const float* gb1  = (const float*)d_in[5];
    const float* gw2  = (const float*)d_in[6];
    const float* gb2  = (const float*)d_in[7];
    const float* nw1  = (const float*)d_in[8];
    const float* nb1  = (const float*)d_in[9];
    const float* nw2  = (const float*)d_in[10];
    const float* nb2  = (const float*)d_in[11];
    const float* qw1  = (const float*)d_in[12];
    const float* qb1  = (const float*)d_in[13];
    const float* qw2  = (const float*)d_in[14];
    const float* qb2  = (const float*)d_in[15];

    char* ws = (char*)d_ws;
    _Float16* q   = (_Float16*)ws;                       // 2 MB
    float* Ppre   = (float*)(ws + 2097152);              // 4 MB
    float* s      = (float*)(ws + 6291456);              // 32 KB
    _Float16* wT1 = (_Float16*)(ws + 6324224);           // 5 x 32 KB + g2h
    _Float16* wT2  = wT1 + 16384;
    _Float16* wTg  = wT2 + 16384;
    _Float16* wTq1 = wTg + 16384;
    _Float16* wTq2 = wTq1 + 16384;
    _Float16* g2h  = wTq2 + 16384;
    float* out = (float*)d_out;

    hipLaunchKernelGGL(prep_w, dim3(128), dim3(128), 0, stream,
                       nw1, nw2, gw1, gw2, qw1, qw2, wT1, wT2, wTg, wTq1, wTq2, g2h);
    hipLaunchKernelGGL(q_kernel, dim3(NB / 128), dim3(512), 0, stream,
                       u, wTq1, wTq2, qb1, qb2, q, Ppre, s);
    hipLaunchKernelGGL(hg_kernel, dim3(HG_GRID), dim3(256), 0, stream,
                       x, batch, q, wT1, wT2, wTg, g2h, nb1, nb2, gb1, gb2, Ppre, s);
    hipLaunchKernelGGL(fin_kernel, dim3(NB / 128), dim3(512), 0, stream,
                       Ppre, s, wT2, nb2, out);
}

// Round 6
// 567.306 us; speedup vs baseline: 1.5703x; 1.0658x over previous
//
#include <hip/hip_runtime.h>
#include <math.h>

#define NN 500000
#define NB 8192
#define GMAX 16
#define HG_GRID 1536
#define HG_NT ((NN + 63) / 64)

typedef _Float16 f16x8 __attribute__((ext_vector_type(8)));
typedef __fp16 fp16x2 __attribute__((ext_vector_type(2)));
typedef float f32x4 __attribute__((ext_vector_type(4)));

__device__ inline f16x8 cvt8(float4 a, float4 b) {
    union { fp16x2 p[4]; f16x8 r; } u;
    u.p[0] = __builtin_amdgcn_cvt_pkrtz(a.x, a.y);
    u.p[1] = __builtin_amdgcn_cvt_pkrtz(a.z, a.w);
    u.p[2] = __builtin_amdgcn_cvt_pkrtz(b.x, b.y);
    u.p[3] = __builtin_amdgcn_cvt_pkrtz(b.z, b.w);
    return u.r;
}

// ---------------- weight prep: W^T as f16 ----------------
__global__ void prep_w(const float* __restrict__ nw1, const float* __restrict__ nw2,
                       const float* __restrict__ gw1, const float* __restrict__ gw2,
                       const float* __restrict__ qw1, const float* __restrict__ qw2,
                       _Float16* __restrict__ wT1, _Float16* __restrict__ wT2,
                       _Float16* __restrict__ wTg, _Float16* __restrict__ wTq1,
                       _Float16* __restrict__ wTq2, _Float16* __restrict__ g2h) {
    int k = blockIdx.x;   // input dim
    int n = threadIdx.x;  // output dim
    wT1[n * 128 + k]  = (_Float16)nw1[k * 128 + n];
    wT2[n * 128 + k]  = (_Float16)nw2[k * 128 + n];
    wTg[n * 128 + k]  = (_Float16)gw1[k * 128 + n];
    wTq1[n * 128 + k] = (_Float16)qw1[k * 128 + n];
    wTq2[n * 128 + k] = (_Float16)qw2[k * 128 + n];
    if (k == 0) g2h[n] = (_Float16)gw2[n];
}

// ---------------- ques MLP via MFMA (q stored f16) + zero Ppre,s ----------------
__launch_bounds__(512, 4)
__global__ void q_kernel(const float* __restrict__ u,
                         const _Float16* __restrict__ wTq1, const _Float16* __restrict__ wTq2,
                         const float* __restrict__ qb1, const float* __restrict__ qb2,
                         _Float16* __restrict__ q, float* __restrict__ Ppre, float* __restrict__ s) {
    __shared__ __align__(16) _Float16 tbuf[128][136];
    const int tid  = threadIdx.x;
    const int wave = tid >> 6;
    const int lane = tid & 63;
    const int lrow = lane & 15;
    const int quad = lane >> 4;
    const int wr   = wave >> 1;
    const int wc   = wave & 1;
    const int row0 = blockIdx.x * 128;
    const int rbase = wr * 32;

    for (int idx = tid; idx < 128 * 128; idx += 512) Ppre[(size_t)row0 * 128 + idx] = 0.f;
    if (tid < 128) s[row0 + tid] = 0.f;

    f32x4 acc[2][4];
    const f32x4 fz = {0.f, 0.f, 0.f, 0.f};
#pragma unroll
    for (int mi = 0; mi < 2; ++mi)
#pragma unroll
        for (int ci = 0; ci < 4; ++ci) acc[mi][ci] = fz;

#pragma unroll
    for (int ki = 0; ki < 4; ++ki) {
        const int k = ki * 32 + quad * 8;
        f16x8 a[2];
#pragma unroll
        for (int mi = 0; mi < 2; ++mi) {
            int r = row0 + rbase + mi * 16 + lrow;
            const float4* up = (const float4*)(u + (size_t)r * 128 + k);
            a[mi] = cvt8(up[0], up[1]);
        }
        f16x8 b[4];
#pragma unroll
        for (int ci = 0; ci < 4; ++ci)
            b[ci] = *(const f16x8*)(wTq1 + (size_t)(wc * 64 + ci * 16 + lrow) * 128 + k);
#pragma unroll
        for (int mi = 0; mi < 2; ++mi)
#pragma unroll
            for (int ci = 0; ci < 4; ++ci)
                acc[mi][ci] = __builtin_amdgcn_mfma_f32_16x16x32_f16(a[mi], b[ci], acc[mi][ci], 0, 0, 0);
    }
#pragma unroll
    for (int ci = 0; ci < 4; ++ci) {
        int c = wc * 64 + ci * 16 + lrow;
        float bv = qb1[c];
#pragma unroll
        for (int mi = 0; mi < 2; ++mi)
#pragma unroll
            for (int i = 0; i < 4; ++i) {
                int r = rbase + mi * 16 + quad * 4 + i;
                tbuf[r][c] = (_Float16)fmaxf(acc[mi][ci][i] + bv, 0.f);
            }
    }
    __syncthreads();

#pragma unroll
    for (int mi = 0; mi < 2; ++mi)
#pragma unroll
        for (int ci = 0; ci < 4; ++ci) acc[mi][ci] = fz;
#pragma unroll
    for (int ki = 0; ki < 4; ++ki) {
        const int k = ki * 32 + quad * 8;
        f16x8 a[2];
#pragma unroll
        for (int mi = 0; mi < 2; ++mi)
            a[mi] = *(const f16x8*)&tbuf[rbase + mi * 16 + lrow][k];
        f16x8 b[4];
#pragma unroll
        for (int ci = 0; ci < 4; ++ci)
            b[ci] = *(const f16x8*)(wTq2 + (size_t)(wc * 64 + ci * 16 + lrow) * 128 + k);
#pragma unroll
        for (int mi = 0; mi < 2; ++mi)
#pragma unroll
            for (int ci = 0; ci < 4; ++ci)
                acc[mi][ci] = __builtin_amdgcn_mfma_f32_16x16x32_f16(a[mi], b[ci], acc[mi][ci], 0, 0, 0);
    }
#pragma unroll
    for (int ci = 0; ci < 4; ++ci) {
        int c = wc * 64 + ci * 16 + lrow;
        float bv = qb2[c];
#pragma unroll
        for (int mi = 0; mi < 2; ++mi)
#pragma unroll
            for (int i = 0; i < 4; ++i) {
                int r = row0 + rbase + mi * 16 + quad * 4 + i;
                q[(size_t)r * 128 + c] = (_Float16)(acc[mi][ci][i] + bv);
            }
    }
}

// ---------------- fused node-MLP + gate + pool-over-t1 (PERSISTENT + split x prefetch) ----------------
// (256,1): VGPR cap = 256/min_waves = 256 (empirical: (256,4)->64, (256,3)->84, (256,2)->128).
// True demand ~145 (R4/R5: 17 then 13 regs spilled at cap 128). Cap 256 -> ZERO spill; residency
// becomes VGPR-bound at ~3 blocks/CU (2048/~150 = 13 waves -> 12). HG_GRID=1536 divides evenly
// by both plausible residencies (512 -> 3 phases, 768 -> 2 phases): no partial-phase tail.
__launch_bounds__(256, 1)
__global__ void hg_kernel(const float* __restrict__ x, const int* __restrict__ batch,
                          const _Float16* __restrict__ qglob,
                          const _Float16* __restrict__ wT1, const _Float16* __restrict__ wT2,
                          const _Float16* __restrict__ wTg, const _Float16* __restrict__ g2h,
                          const float* __restrict__ nb1, const float* __restrict__ nb2,
                          const float* __restrict__ gb1, const float* __restrict__ gb2,
                          float* __restrict__ Ppre, float* __restrict__ s) {
    __shared__ __align__(16) _Float16 t1buf[64][136];    // persists: M1 out -> M2 in -> pooling B
    __shared__ __align__(16) _Float16 scratch[64][136];  // gin only
    __shared__ __align__(16) _Float16 qsE[GMAX][136];    // union: qs (f16) then E selector
    __shared__ float gpart[2][64];
    __shared__ float sacc[GMAX];
    __shared__ int batch_t[64];
    __shared__ int maxrel_sh;

    const int tid  = threadIdx.x;
    const int wave = tid >> 6;   // 0..3
    const int lane = tid & 63;
    const int lrow = lane & 15;
    const int quad = lane >> 4;
    const int wr   = wave >> 1;  // 0..1
    const int wc   = wave & 1;
    const int rbase = wr * 32;
    const int blk  = (int)blockIdx.x;

    const f32x4 fz = {0.f, 0.f, 0.f, 0.f};

    // ---- prologue: load + convert first tile; prefetch first batch window ----
    f16x8 a16[4][2];   // CURRENT tile's A fragments (f16, 32 VGPRs) — crosses loop top
    {
        const int r0 = blk * 64;
#pragma unroll
        for (int ki = 0; ki < 4; ++ki)
#pragma unroll
            for (int mi = 0; mi < 2; ++mi) {
                int r = min(r0 + rbase + mi * 16 + lrow, NN - 1);
                const float4* xp = (const float4*)(x + (size_t)r * 128 + ki * 32 + quad * 8);
                a16[ki][mi] = cvt8(xp[0], xp[1]);
            }
    }
    int bv = 0;
    if (wave == 0) {
        int i0 = blk * 64 + lane;
        bv = batch[min(i0, NN - 1)];
    }

    for (int t = blk; t < HG_NT; t += HG_GRID) {
        const int row0  = t * 64;
        const int rown0 = (t + HG_GRID) * 64;  // next tile's base (loads are row-clamped)

        // ---- setup: batch window, b_lo, maxrel (wave 0 only; uses prefetched bv) ----
        if (wave == 0) {
            batch_t[lane] = bv;
            int b0 = __shfl(bv, 0, 64);
            int rel = bv - b0;
#pragma unroll
            for (int off = 32; off >= 1; off >>= 1) rel = max(rel, __shfl_xor(rel, off, 64));
            if (lane == 0) maxrel_sh = rel;
        }
        __syncthreads();  // bar0 (also orders prev-iter qsE/t1buf reads vs this iter's writes)
        const int b_lo = batch_t[0];
        const int gcnt = min(maxrel_sh + 1, GMAX);

        // prefetch next tile's batch window (arrives during this tile's compute)
        if (wave == 0) bv = batch[min(rown0 + lane, NN - 1)];

        // qs: gather q rows for graphs in window (consumed after bar1)
        for (int idx = tid; idx < gcnt * 16; idx += 256)
            *(f16x8*)&qsE[idx >> 4][(idx & 15) * 8] =
                *(const f16x8*)(qglob + (size_t)(b_lo + (idx >> 4)) * 128 + (idx & 15) * 8);

        f32x4 acc[2][4];
#pragma unroll
        for (int mi = 0; mi < 2; ++mi)
#pragma unroll
            for (int ci = 0; ci < 4; ++ci) acc[mi][ci] = fz;

        // ===== M1: t1 = relu(x @ w1 + b1) -> t1buf (uses a16 prepared last iter) =====
#pragma unroll
        for (int ki = 0; ki < 4; ++ki) {
            const int k = ki * 32 + quad * 8;
            f16x8 b[4];
#pragma unroll
            for (int ci = 0; ci < 4; ++ci)
                b[ci] = *(const f16x8*)(wT1 + (size_t)(wc * 64 + ci * 16 + lrow) * 128 + k);
#pragma unroll
            for (int mi = 0; mi < 2; ++mi)
#pragma unroll
                for (int ci = 0; ci < 4; ++ci)
                    acc[mi][ci] = __builtin_amdgcn_mfma_f32_16x16x32_f16(a16[ki][mi], b[ci], acc[mi][ci], 0, 0, 0);
        }
#pragma unroll
        for (int ci = 0; ci < 4; ++ci) {
            int c = wc * 64 + ci * 16 + lrow;
            float bvv = nb1[c];
#pragma unroll
            for (int mi = 0; mi < 2; ++mi)
#pragma unroll
                for (int i = 0; i < 4; ++i) {
                    int r = rbase + mi * 16 + quad * 4 + i;
                    t1buf[r][c] = (_Float16)fmaxf(acc[mi][ci][i] + bvv, 0.f);
                }
        }
        __syncthreads();  // bar1: t1 + qs visible

        // ---- issue chunk A of next tile's x (ki=0,1; 32 f32 regs, live bar1->bar2) ----
        __builtin_amdgcn_sched_barrier(0);
        float4 xrawA[2][2][2];
#pragma unroll
        for (int ki = 0; ki < 2; ++ki)
#pragma unroll
            for (int mi = 0; mi < 2; ++mi) {
                int r = min(rown0 + rbase + mi * 16 + lrow, NN - 1);
                const float4* xp = (const float4*)(x + (size_t)r * 128 + ki * 32 + quad * 8);
                xrawA[ki][mi][0] = xp[0];
                xrawA[ki][mi][1] = xp[1];
            }

        // ===== M2: h = t1 @ w2 + b2 ; gin = q[batch] * h -> scratch =====
#pragma unroll
        for (int mi = 0; mi < 2; ++mi)
#pragma unroll
            for (int ci = 0; ci < 4; ++ci) acc[mi][ci] = fz;
#pragma unroll
        for (int ki = 0; ki < 4; ++ki) {
            const int k = ki * 32 + quad * 8;
            f16x8 a[2];
#pragma unroll
            for (int mi = 0; mi < 2; ++mi)
                a[mi] = *(const f16x8*)&t1buf[rbase + mi * 16 + lrow][k];
            f16x8 b[4];
#pragma unroll
            for (int ci = 0; ci < 4; ++ci)
                b[ci] = *(const f16x8*)(wT2 + (size_t)(wc * 64 + ci * 16 + lrow) * 128 + k);
#pragma unroll
            for (int mi = 0; mi < 2; ++mi)
#pragma unroll
                for (int ci = 0; ci < 4; ++ci)
                    acc[mi][ci] = __builtin_amdgcn_mfma_f32_16x16x32_f16(a[mi], b[ci], acc[mi][ci], 0, 0, 0);
        }
#pragma unroll
        for (int ci = 0; ci < 4; ++ci) {
            int c = wc * 64 + ci * 16 + lrow;
            float bvv = nb2[c];
#pragma unroll
            for (int mi = 0; mi < 2; ++mi)
#pragma unroll
                for (int i = 0; i < 4; ++i) {
                    int r = rbase + mi * 16 + quad * 4 + i;
                    float h = acc[mi][ci][i] + bvv;
                    int g = batch_t[r] - b_lo;  // recomputed at use (saves 8 live regs)
                    float qv = (g < GMAX) ? (float)qsE[g][c]
                                          : (float)qglob[(size_t)(b_lo + g) * 128 + c];
                    scratch[r][c] = (_Float16)(qv * h);
                }
        }
        __syncthreads();  // bar2: gin visible, qs reads done

        // convert chunk A now (vmcnt wait covered by M2's MFMAs); frees xrawA regs
#pragma unroll
        for (int ki = 0; ki < 2; ++ki)
#pragma unroll
            for (int mi = 0; mi < 2; ++mi)
                a16[ki][mi] = cvt8(xrawA[ki][mi][0], xrawA[ki][mi][1]);

        // zero E + sacc (visible after bar3)
        for (int idx = tid; idx < GMAX * 136 / 2; idx += 256) ((float*)qsE)[idx] = 0.f;
        if (tid < GMAX) sacc[tid] = 0.f;

        // ===== M3: t2 = relu(gin @ gw1 + gb1); gate partial via gw2 dot + shuffle =====
#pragma unroll
        for (int mi = 0; mi < 2; ++mi)
#pragma unroll
            for (int ci = 0; ci < 4; ++ci) acc[mi][ci] = fz;
        float g2hreg[4];
#pragma unroll
        for (int ci = 0; ci < 4; ++ci) g2hreg[ci] = (float)g2h[wc * 64 + ci * 16 + lrow];
#pragma unroll
        for (int ki = 0; ki < 4; ++ki) {
            const int k = ki * 32 + quad * 8;
            f16x8 a[2];
#pragma unroll
            for (int mi = 0; mi < 2; ++mi)
                a[mi] = *(const f16x8*)&scratch[rbase + mi * 16 + lrow][k];
            f16x8 b[4];
#pragma unroll
            for (int ci = 0; ci < 4; ++ci)
                b[ci] = *(const f16x8*)(wTg + (size_t)(wc * 64 + ci * 16 + lrow) * 128 + k);
#pragma unroll
            for (int mi = 0; mi < 2; ++mi)
#pragma unroll
                for (int ci = 0; ci < 4; ++ci)
                    acc[mi][ci] = __builtin_amdgcn_mfma_f32_16x16x32_f16(a[mi], b[ci], acc[mi][ci], 0, 0, 0);
        }

        // ---- issue chunk B of next tile's x (ki=2,3; live M3-epilogue -> pool end) ----
        __builtin_amdgcn_sched_barrier(0);
        float4 xrawB[2][2][2];
#pragma unroll
        for (int ki = 0; ki < 2; ++ki)
#pragma unroll
            for (int mi = 0; mi < 2; ++mi) {
                int r = min(rown0 + rbase + mi * 16 + lrow, NN - 1);
                const float4* xp = (const float4*)(x + (size_t)r * 128 + (ki + 2) * 32 + quad * 8);
                xrawB[ki][mi][0] = xp[0];
                xrawB[ki][mi][1] = xp[1];
            }

        float p[2][4] = {{0.f, 0.f, 0.f, 0.f}, {0.f, 0.f, 0.f, 0.f}};
#pragma unroll
        for (int ci = 0; ci < 4; ++ci) {
            int c = wc * 64 + ci * 16 + lrow;
            float bvv = gb1[c];
            float w = g2hreg[ci];
#pragma unroll
            for (int mi = 0; mi < 2; ++mi)
#pragma unroll
                for (int i = 0; i < 4; ++i)
                    p[mi][i] = fmaf(fmaxf(acc[mi][ci][i] + bvv, 0.f), w, p[mi][i]);
        }
#pragma unroll
        for (int off = 1; off <= 8; off <<= 1)
#pragma unroll
            for (int mi = 0; mi < 2; ++mi)
#pragma unroll
                for (int i = 0; i < 4; ++i)
                    p[mi][i] += __shfl_xor(p[mi][i], off, 64);
        if (lrow == 0) {
#pragma unroll
            for (int mi = 0; mi < 2; ++mi)
#pragma unroll
                for (int i = 0; i < 4; ++i)
                    gpart[wc][rbase + mi * 16 + quad * 4 + i] = p[mi][i];
        }
        __syncthreads();  // bar3: gpart + E-zero visible

        // ===== gate -> e -> E selector (one thread per row) =====
        const float gb2v = gb2[0];
        if (tid < 64) {
            int r = tid;
            int g = batch_t[r] - b_lo;
            bool valid = (row0 + r) < NN;
            float e = valid ? __expf(gpart[0][r] + gpart[1][r] + gb2v) : 0.f;
            if (g < GMAX) {
                qsE[g][r] = (_Float16)e;
                atomicAdd(&sacc[g], e);
            } else if (valid) {  // pathological >16 graphs per 64-row window
                atomicAdd(&s[b_lo + g], e);
                for (int c = 0; c < 128; ++c)
                    atomicAdd(&Ppre[(size_t)(b_lo + g) * 128 + c], e * (float)t1buf[r][c]);
            }
        }
        __syncthreads();  // bar4: E visible

        // ===== pooling: Ppre_tile = E(16x64) @ T1(64x128), each wave 32 cols =====
        f16x8 aE[2];
#pragma unroll
        for (int ki = 0; ki < 2; ++ki)
            aE[ki] = *(const f16x8*)&qsE[lrow][ki * 32 + quad * 8];
        f32x4 pacc[2] = {fz, fz};
#pragma unroll
        for (int ci2 = 0; ci2 < 2; ++ci2) {
            int col = wave * 32 + ci2 * 16 + lrow;
#pragma unroll
            for (int ki = 0; ki < 2; ++ki) {
                f16x8 bh;
#pragma unroll
                for (int j = 0; j < 8; ++j) bh[j] = t1buf[ki * 32 + quad * 8 + j][col];
                pacc[ci2] = __builtin_amdgcn_mfma_f32_16x16x32_f16(aE[ki], bh, pacc[ci2], 0, 0, 0);
            }
        }
#pragma unroll
        for (int ci2 = 0; ci2 < 2; ++ci2)
#pragma unroll
            for (int i = 0; i < 4; ++i) {
                int g = quad * 4 + i;
                if (g < gcnt)
                    atomicAdd(&Ppre[(size_t)(b_lo + g) * 128 + wave * 32 + ci2 * 16 + lrow], pacc[ci2][i]);
            }

        // convert chunk B (loads long since landed; frees xrawB before next iter)
#pragma unroll
        for (int ki = 0; ki < 2; ++ki)
#pragma unroll
            for (int mi = 0; mi < 2; ++mi)
                a16[ki + 2][mi] = cvt8(xrawB[ki][mi][0], xrawB[ki][mi][1]);

        if (tid < gcnt) atomicAdd(&s[b_lo + tid], sacc[tid]);
    }
}

// ---------------- finalize: out = (Ppre @ w2 + s*b2) / (s + eps) ----------------
__launch_bounds__(512, 4)
__global__ void fin_kernel(const float* __restrict__ Ppre, const float* __restrict__ s,
                           const _Float16* __restrict__ wT2, const float* __restrict__ nb2,
                           float* __restrict__ out) {
    const int tid  = threadIdx.x;
    const int wave = tid >> 6;
    const int lane = tid & 63;
    const int lrow = lane & 15;
    const int quad = lane >> 4;
    const int wr   = wave >> 1;
    const int wc   = wave & 1;
    const int row0 = blockIdx.x * 128;
    const int rbase = wr * 32;

    f32x4 acc[2][4];
    const f32x4 fz = {0.f, 0.f, 0.f, 0.f};
#pragma unroll
    for (int mi = 0; mi < 2; ++mi)
#pragma unroll
        for (int ci = 0; ci < 4; ++ci) acc[mi][ci] = fz;
#pragma unroll
    for (int ki = 0; ki < 4; ++ki) {
        const int k = ki * 32 + quad * 8;
        f16x8 a[2];
#pragma unroll
        for (int mi = 0; mi < 2; ++mi) {
            int r = row0 + rbase + mi * 16 + lrow;
            const float4* pp = (const float4*)(Ppre + (size_t)r * 128 + k);
            a[mi] = cvt8(pp[0], pp[1]);
        }
        f16x8 b[4];
#pragma unroll
        for (int ci = 0; ci < 4; ++ci)
            b[ci] = *(const f16x8*)(wT2 + (size_t)(wc * 64 + ci * 16 + lrow) * 128 + k);
#pragma unroll
        for (int mi = 0; mi < 2; ++mi)
#pragma unroll
            for (int ci = 0; ci < 4; ++ci)
                acc[mi][ci] = __builtin_amdgcn_mfma_f32_16x16x32_f16(a[mi], b[ci], acc[mi][ci], 0, 0, 0);
    }
    float sv[2][4], rinv[2][4];
#pragma unroll
    for (int mi = 0; mi < 2; ++mi)
#pragma unroll
        for (int i = 0; i < 4; ++i) {
            int r = row0 + rbase + mi * 16 + quad * 4 + i;
            sv[mi][i] = s[r];
            rinv[mi][i] = 1.f / (sv[mi][i] + 1e-16f);
        }
#pragma unroll
    for (int ci = 0; ci < 4; ++ci) {
        int c = wc * 64 + ci * 16 + lrow;
        float bv = nb2[c];
#pragma unroll
        for (int mi = 0; mi < 2; ++mi)
#pragma unroll
            for (int i = 0; i < 4; ++i) {
                int r = row0 + rbase + mi * 16 + quad * 4 + i;
                out[(size_t)r * 128 + c] = (acc[mi][ci][i] + sv[mi][i] * bv) * rinv[mi][i];
            }
    }
}

extern "C" void kernel_launch(void* const* d_in, const int* in_sizes, int n_in,
                              void* d_out, int out_size, void* d_ws, size_t ws_size,
                              hipStream_t stream) {
    const float* x    = (const float*)d_in[0];
    const float* u    = (const float*)d_in[1];
    const int* batch  = (const int*)d_in[2];
    const float* gw1  = (const float*)d_in[4];
    const float* gb1  = (const float*)d_in[5];
    const float* gw2  = (const float*)d_in[6];
    const float* gb2  = (const float*)d_in[7];
    const float* nw1  = (const float*)d_in[8];
    const float* nb1  = (const float*)d_in[9];
    const float* nw2  = (const float*)d_in[10];
    const float* nb2  = (const float*)d_in[11];
    const float* qw1  = (const float*)d_in[12];
    const float* qb1  = (const float*)d_in[13];
    const float* qw2  = (const float*)d_in[14];
    const float* qb2  = (const float*)d_in[15];

    char* ws = (char*)d_ws;
    _Float16* q   = (_Float16*)ws;                       // 2 MB
    float* Ppre   = (float*)(ws + 2097152);              // 4 MB
    float* s      = (float*)(ws + 6291456);              // 32 KB
    _Float16* wT1 = (_Float16*)(ws + 6324224);           // 5 x 32 KB + g2h
    _Float16* wT2  = wT1 + 16384;
    _Float16* wTg  = wT2 + 16384;
    _Float16* wTq1 = wTg + 16384;
    _Float16* wTq2 = wTq1 + 16384;
    _Float16* g2h  = wTq2 + 16384;
    float* out = (float*)d_out;

    hipLaunchKernelGGL(prep_w, dim3(128), dim3(128), 0, stream,
                       nw1, nw2, gw1, gw2, qw1, qw2, wT1, wT2, wTg, wTq1, wTq2, g2h);
    hipLaunchKernelGGL(q_kernel, dim3(NB / 128), dim3(512), 0, stream,
                       u, wTq1, wTq2, qb1, qb2, q, Ppre, s);
    hipLaunchKernelGGL(hg_kernel, dim3(HG_GRID), dim3(256), 0, stream,
                       x, batch, q, wT1, wT2, wTg, g2h, nb1, nb2, gb1, gb2, Ppre, s);
    hipLaunchKernelGGL(fin_kernel, dim3(NB / 128), dim3(512), 0, stream,
                       Ppre, s, wT2, nb2, out);
}